// Round 2
// baseline (2613.201 us; speedup 1.0000x reference)
//
#include <hip/hip_runtime.h>

#define N_SITES  100000
#define N_BONDS  800000
#define N_GRAPHS 1000

// ---------- LDS staging helpers (fp32) ----------
template<int CNT>
__device__ __forceinline__ void stage_w(float* dst, const float* __restrict__ src, int tid, int nth){
  for (int i = tid; i < CNT; i += nth) dst[i] = src[i];
}
__device__ __forceinline__ void stage_b(float* dst, const float* __restrict__ src, int n, int tid){
  if (tid < n) dst[tid] = src[tid];
}

// acc[r] += sum_k x[r*XS + k] * W[k*N + j]
// W in LDS [K][N]: lane-consecutive reads (2-way bank alias = free).
// x in LDS, read as same-address float4 broadcasts (conflict-free).
template<int K, int N, int R, int XS>
__device__ __forceinline__ void layerR(const float* __restrict__ W,
                                       const float* __restrict__ x,
                                       float* __restrict__ acc, int j)
{
  #pragma unroll
  for (int k = 0; k < K; k += 4){
    float w0 = W[(k+0)*N + j];
    float w1 = W[(k+1)*N + j];
    float w2 = W[(k+2)*N + j];
    float w3 = W[(k+3)*N + j];
    #pragma unroll
    for (int r = 0; r < R; ++r){
      float4 xv = *(const float4*)(x + r*XS + k);
      acc[r] = fmaf(xv.x, w0, acc[r]);
      acc[r] = fmaf(xv.y, w1, acc[r]);
      acc[r] = fmaf(xv.z, w2, acc[r]);
      acc[r] = fmaf(xv.w, w3, acc[r]);
    }
  }
}

__device__ __forceinline__ int lbound(const int* __restrict__ a, int n, int v){
  int lo = 0, hi = n;
  while (lo < hi){ int m = (lo+hi) >> 1; if (a[m] < v) lo = m+1; else hi = m; }
  return lo;
}

// ---------- kernel 1: states path prep (1000 rows) ----------
// Wave-private x/h slices; the only barrier is after cooperative weight
// staging (cross-lane staging deps are invisible to per-lane alias analysis,
// so the barrier is REQUIRED there — see round-1 failure).
__global__ __launch_bounds__(256) void prep_small_kernel(
    const float* __restrict__ states,
    const float* __restrict__ w1, const float* __restrict__ b1,
    const float* __restrict__ w2, const float* __restrict__ b2,
    const float* __restrict__ w_bu1, const float* __restrict__ b_bu1,
    const float* __restrict__ w_su1, const float* __restrict__ b_su1,
    const float* __restrict__ w_stu1, const float* __restrict__ b_stu1,
    float* __restrict__ states2, float* __restrict__ statec_bu,
    float* __restrict__ statec_su, float* __restrict__ statec_stu)
{
  __shared__ float W1[4096], W2[4096], WD[4096], WsuC[4096], WstuC[4096];
  __shared__ float B1[64], B2[64], Bbu[64], Bsu[64], Bstu[64];
  __shared__ alignas(16) float xs[4][64];
  __shared__ alignas(16) float hs[4][64];
  int tid = threadIdx.x;
  stage_w<4096>(W1,    w1,              tid, 256);
  stage_w<4096>(W2,    w2,              tid, 256);
  stage_w<4096>(WD,    w_bu1 + 192*64,  tid, 256);
  stage_w<4096>(WsuC,  w_su1 + 128*64,  tid, 256);
  stage_w<4096>(WstuC, w_stu1 + 128*64, tid, 256);
  stage_b(B1, b1, 64, tid);  stage_b(B2, b2, 64, tid);
  stage_b(Bbu, b_bu1, 64, tid); stage_b(Bsu, b_su1, 64, tid); stage_b(Bstu, b_stu1, 64, tid);
  __syncthreads();
  int w = tid >> 6, lane = tid & 63;
  int g = blockIdx.x*4 + w;                       // 250 blocks * 4 = exactly 1000
  xs[w][lane] = states[(size_t)g*64 + lane];
  float a = B1[lane];
  layerR<64,64,1,64>(W1, xs[w], &a, lane);
  hs[w][lane] = fmaxf(a, 0.f);
  a = B2[lane];
  layerR<64,64,1,64>(W2, hs[w], &a, lane);
  float s2 = fmaxf(a, 0.f);
  xs[w][lane] = s2;
  size_t o = (size_t)g*64 + lane;
  float abu = Bbu[lane], asu = Bsu[lane], astu = Bstu[lane];
  layerR<64,64,1,64>(WD,    xs[w], &abu,  lane);
  layerR<64,64,1,64>(WsuC,  xs[w], &asu,  lane);
  layerR<64,64,1,64>(WstuC, xs[w], &astu, lane);
  states2[o]    = s2;
  statec_bu[o]  = abu;
  statec_su[o]  = asu;
  statec_stu[o] = astu;
}

// ---------- kernel 2: sites pre-MLP (100000 rows) -> fp32 sites2 ----------
__global__ __launch_bounds__(256) void sites_pre_kernel(
    const float* __restrict__ sites,
    const float* __restrict__ w1, const float* __restrict__ b1,
    const float* __restrict__ w2, const float* __restrict__ b2,
    float* __restrict__ sites2)
{
  __shared__ float W1[4096], W2[4096];
  __shared__ float B1[64], B2[64];
  __shared__ alignas(16) float xs[4][4][64];
  __shared__ alignas(16) float hs[4][4][64];
  int tid = threadIdx.x;
  stage_w<4096>(W1, w1, tid, 256);
  stage_w<4096>(W2, w2, tid, 256);
  stage_b(B1, b1, 64, tid); stage_b(B2, b2, 64, tid);
  __syncthreads();
  int w = tid >> 6, lane = tid & 63;
  int wgid = blockIdx.x*4 + w;                     // 1024 blocks * 4 waves = 4096
  for (int n = 0; n < 7; ++n){                     // 7*4096 >= 25000 groups of 4 sites
    int G = n*4096 + wgid;
    if (G >= 25000) break;
    #pragma unroll
    for (int r = 0; r < 4; ++r)
      xs[w][r][lane] = sites[((size_t)(4*G + r))*64 + lane];
    {
      float a[4] = {B1[lane], B1[lane], B1[lane], B1[lane]};
      layerR<64,64,4,64>(W1, &xs[w][0][0], a, lane);
      #pragma unroll
      for (int r = 0; r < 4; ++r) hs[w][r][lane] = fmaxf(a[r], 0.f);
    }
    {
      float a[4] = {B2[lane], B2[lane], B2[lane], B2[lane]};
      layerR<64,64,4,64>(W2, &hs[w][0][0], a, lane);
      #pragma unroll
      for (int r = 0; r < 4; ++r)
        sites2[((size_t)(4*G + r))*64 + lane] = fmaxf(a[r], 0.f);
    }
  }
}

// ---------- kernel 3: bond kernel (fused bonds pre-MLP + gather + bond update) ----------
// 1024 threads = 16 waves share ONE copy of the 96 KiB of weights.
// Per-wave scratch time-shared -> LDS = 152.9 KiB -> 16 waves/CU = 4 waves/SIMD.
// No inner barriers: every x/h buffer is a wave-private slice (validated:
// bonds output passed in round 1).
__global__ __launch_bounds__(1024) void bond_kernel(
    const float* __restrict__ bonds,
    const float* __restrict__ wb1, const float* __restrict__ bb1,
    const float* __restrict__ wb2, const float* __restrict__ bb2,
    const float* __restrict__ w_bu1,
    const float* __restrict__ w_bu2, const float* __restrict__ b_bu2,
    const float* __restrict__ w_bu3, const float* __restrict__ b_bu3,
    const int* __restrict__ idx1, const int* __restrict__ idx2, const int* __restrict__ g2b,
    const float* __restrict__ sites2, const float* __restrict__ statec_bu,
    float* __restrict__ bonds_pool, int* __restrict__ cnt_pool, float* __restrict__ bonds_g,
    float* __restrict__ out_bonds)
{
  __shared__ float W1[4096], W2[4096], WA[4096], WB[4096], WC[4096];
  __shared__ float WU2[2048], WU3[2048];
  __shared__ float Bb1[64], Bb2[64], Bu2[32], Bu3[64];
  __shared__ alignas(16) float xs[16][4][64];   // bonds-in, then bonds2
  __shared__ alignas(16) float xg[16][4][64];   // scratch: s1 then s2
  __shared__ alignas(16) float hs[16][4][64];
  __shared__ alignas(16) float h2[16][4][32];
  int tid = threadIdx.x;
  stage_w<4096>(W1, wb1,            tid, 1024);
  stage_w<4096>(W2, wb2,            tid, 1024);
  stage_w<4096>(WA, w_bu1,          tid, 1024);
  stage_w<4096>(WB, w_bu1 + 64*64,  tid, 1024);
  stage_w<4096>(WC, w_bu1 + 128*64, tid, 1024);
  stage_w<2048>(WU2, w_bu2,         tid, 1024);
  stage_w<2048>(WU3, w_bu3,         tid, 1024);
  stage_b(Bb1, bb1, 64, tid); stage_b(Bb2, bb2, 64, tid);
  stage_b(Bu2, b_bu2, 32, tid); stage_b(Bu3, b_bu3, 64, tid);
  __syncthreads();
  int w = tid >> 6, lane = tid & 63;
  int ebase = blockIdx.x*1024 + w*64;   // wave owns 64 CONTIGUOUS bonds (g2b sorted)
  if (ebase >= N_BONDS) return;         // tail block: inactive waves exit after barrier
  float gacc = 0.f; int cur_g = -1;
  for (int it = 0; it < 16; ++it){
    int e0 = ebase + it*4;
    int i1a[4], i2a[4], gg[4];
    #pragma unroll
    for (int r = 0; r < 4; ++r){
      int e = e0 + r;
      i1a[r] = idx1[e]; i2a[r] = idx2[e]; gg[r] = g2b[e];
    }
    float vb[4], v1[4], v2[4];
    #pragma unroll
    for (int r = 0; r < 4; ++r){
      vb[r] = bonds[(size_t)(e0+r)*64 + lane];
      v1[r] = sites2[(size_t)i1a[r]*64 + lane];
      v2[r] = sites2[(size_t)i2a[r]*64 + lane];
    }
    #pragma unroll
    for (int r = 0; r < 4; ++r) xs[w][r][lane] = vb[r];
    // bonds pre-MLP layer 1
    {
      float a[4] = {Bb1[lane], Bb1[lane], Bb1[lane], Bb1[lane]};
      layerR<64,64,4,64>(W1, &xs[w][0][0], a, lane);
      #pragma unroll
      for (int r = 0; r < 4; ++r) hs[w][r][lane] = fmaxf(a[r], 0.f);
    }
    // bonds pre-MLP layer 2 -> bonds2 (residual), stash into xs
    float b2v[4];
    {
      float a[4] = {Bb2[lane], Bb2[lane], Bb2[lane], Bb2[lane]};
      layerR<64,64,4,64>(W2, &hs[w][0][0], a, lane);
      #pragma unroll
      for (int r = 0; r < 4; ++r) b2v[r] = fmaxf(a[r], 0.f);
    }
    #pragma unroll
    for (int r = 0; r < 4; ++r) xs[w][r][lane] = b2v[r];
    // bond-update fc1: A*s1 + B*s2 + C*bonds2 + (state slice incl. bias)
    {
      float a[4];
      #pragma unroll
      for (int r = 0; r < 4; ++r) a[r] = statec_bu[(size_t)gg[r]*64 + lane];
      #pragma unroll
      for (int r = 0; r < 4; ++r) xg[w][r][lane] = v1[r];
      layerR<64,64,4,64>(WA, &xg[w][0][0], a, lane);
      #pragma unroll
      for (int r = 0; r < 4; ++r) xg[w][r][lane] = v2[r];   // wave-ordered after WA reads
      layerR<64,64,4,64>(WB, &xg[w][0][0], a, lane);
      layerR<64,64,4,64>(WC, &xs[w][0][0], a, lane);
      #pragma unroll
      for (int r = 0; r < 4; ++r) hs[w][r][lane] = fmaxf(a[r], 0.f);
    }
    // bond-update fc2 (64 -> 32); all lanes compute j=lane&31, low lanes write
    {
      int j = lane & 31;
      float a[4] = {Bu2[j], Bu2[j], Bu2[j], Bu2[j]};
      layerR<64,32,4,64>(WU2, &hs[w][0][0], a, j);
      if (lane < 32){
        #pragma unroll
        for (int r = 0; r < 4; ++r) h2[w][r][lane] = fmaxf(a[r], 0.f);
      }
    }
    // bond-update fc3 (32 -> 64) + epilogue
    {
      float a[4] = {Bu3[lane], Bu3[lane], Bu3[lane], Bu3[lane]};
      layerR<32,64,4,32>(WU3, &h2[w][0][0], a, lane);
      #pragma unroll
      for (int r = 0; r < 4; ++r){
        float bnew = fmaxf(a[r], 0.f);
        int e = e0 + r;
        out_bonds[(size_t)e*64 + lane] = bnew + b2v[r];
        atomicAdd(&bonds_pool[(size_t)i1a[r]*64 + lane], bnew);
        if (lane == 0) atomicAdd(&cnt_pool[i1a[r]], 1);
        if (gg[r] != cur_g){
          if (cur_g >= 0) atomicAdd(&bonds_g[(size_t)cur_g*64 + lane], gacc);
          cur_g = gg[r]; gacc = 0.f;
        }
        gacc += bnew;
      }
    }
  }
  if (cur_g >= 0) atomicAdd(&bonds_g[(size_t)cur_g*64 + lane], gacc);
}

// ---------- kernel 4: site update (100000 rows) ----------
// 512 threads = 8 waves, 16 rows/wave -> LDS 76.4 KiB -> 2 blocks/CU = 4 waves/SIMD.
// 6250 active waves x 16 rows = exactly 100000: no per-row guards.
// (validated: sites output passed in round 1)
__global__ __launch_bounds__(512, 4) void site_kernel(
    const float* __restrict__ sites2, const float* __restrict__ bonds_pool, const int* __restrict__ cnt_pool,
    const int* __restrict__ g2s, const float* __restrict__ statec_su,
    const float* __restrict__ w_su1, const float* __restrict__ w_su2, const float* __restrict__ b_su2,
    const float* __restrict__ w_su3, const float* __restrict__ b_su3,
    float* __restrict__ sites_g, float* __restrict__ out_sites)
{
  __shared__ float W1a[4096], W1b[4096], W2[2048], W3[2048];
  __shared__ float B2s[32], B3s[64];
  __shared__ alignas(16) float xg[8][4][64];   // scratch: pooled bonds, then sites2
  __shared__ alignas(16) float hs[8][4][64];
  __shared__ alignas(16) float h2[8][4][32];
  int tid = threadIdx.x;
  stage_w<4096>(W1a, w_su1,         tid, 512);
  stage_w<4096>(W1b, w_su1 + 64*64, tid, 512);
  stage_w<2048>(W2,  w_su2,         tid, 512);
  stage_w<2048>(W3,  w_su3,         tid, 512);
  stage_b(B2s, b_su2, 32, tid); stage_b(B3s, b_su3, 64, tid);
  __syncthreads();
  int w = tid >> 6, lane = tid & 63;
  int sbase = (blockIdx.x*8 + w)*16;    // contiguous sites per wave (g2s sorted)
  if (sbase >= N_SITES) return;
  float gacc = 0.f; int cur_g = -1;
  for (int it = 0; it < 4; ++it){
    int s0 = sbase + it*4;
    int gg[4]; float s2v[4], pv[4];
    #pragma unroll
    for (int r = 0; r < 4; ++r){
      int s = s0 + r;
      gg[r] = g2s[s];
      float inv = 1.f / fmaxf((float)cnt_pool[s], 1.f);
      pv[r]  = bonds_pool[(size_t)s*64 + lane] * inv;
      s2v[r] = sites2[(size_t)s*64 + lane];
    }
    {
      float a[4];
      #pragma unroll
      for (int r = 0; r < 4; ++r) a[r] = statec_su[(size_t)gg[r]*64 + lane];
      #pragma unroll
      for (int r = 0; r < 4; ++r) xg[w][r][lane] = pv[r];
      layerR<64,64,4,64>(W1a, &xg[w][0][0], a, lane);
      #pragma unroll
      for (int r = 0; r < 4; ++r) xg[w][r][lane] = s2v[r];  // wave-ordered after W1a reads
      layerR<64,64,4,64>(W1b, &xg[w][0][0], a, lane);
      #pragma unroll
      for (int r = 0; r < 4; ++r) hs[w][r][lane] = fmaxf(a[r], 0.f);
    }
    {
      int j = lane & 31;
      float a[4] = {B2s[j], B2s[j], B2s[j], B2s[j]};
      layerR<64,32,4,64>(W2, &hs[w][0][0], a, j);
      if (lane < 32){
        #pragma unroll
        for (int r = 0; r < 4; ++r) h2[w][r][lane] = fmaxf(a[r], 0.f);
      }
    }
    {
      float a[4] = {B3s[lane], B3s[lane], B3s[lane], B3s[lane]};
      layerR<32,64,4,32>(W3, &h2[w][0][0], a, lane);
      #pragma unroll
      for (int r = 0; r < 4; ++r){
        int s = s0 + r;
        float snew = fmaxf(a[r], 0.f);
        out_sites[(size_t)s*64 + lane] = snew + s2v[r];
        if (gg[r] != cur_g){
          if (cur_g >= 0) atomicAdd(&sites_g[(size_t)cur_g*64 + lane], gacc);
          cur_g = gg[r]; gacc = 0.f;
        }
        gacc += snew;
      }
    }
  }
  if (cur_g >= 0) atomicAdd(&sites_g[(size_t)cur_g*64 + lane], gacc);
}

// ---------- kernel 5: state update (1000 graphs, one wave each) ----------
// Round-1 failure was HERE: removing the barriers let the scheduler hoist
// cross-lane LDS reads above the cooperative staging writes (per-lane alias
// analysis can't see lane->lane deps). Barriers restored — on a single-wave
// block they lower to cheap waitcnt fences.
__global__ __launch_bounds__(64) void state_kernel(
    const float* __restrict__ states2, const float* __restrict__ bonds_g, const float* __restrict__ sites_g,
    const int* __restrict__ g2b, const int* __restrict__ g2s,
    const float* __restrict__ w_stu1, const float* __restrict__ w_stu2, const float* __restrict__ b_stu2,
    const float* __restrict__ w_stu3, const float* __restrict__ b_stu3,
    const float* __restrict__ statec_stu, float* __restrict__ out_states)
{
  __shared__ float W1a[4096], W1b[4096], W2[2048], W3[2048];
  __shared__ float B2s[32], B3s[64];
  __shared__ alignas(16) float xb[64], xsit[64], hsx[64], h2x[32];
  __shared__ int cnts[2];
  int lane = threadIdx.x; int g = blockIdx.x;
  stage_w<4096>(W1a, w_stu1,         lane, 64);
  stage_w<4096>(W1b, w_stu1 + 64*64, lane, 64);
  stage_w<2048>(W2,  w_stu2,         lane, 64);
  stage_w<2048>(W3,  w_stu3,         lane, 64);
  stage_b(B2s, b_stu2, 32, lane); stage_b(B3s, b_stu3, 64, lane);
  if (lane == 0){
    cnts[0] = lbound(g2b, N_BONDS, g+1) - lbound(g2b, N_BONDS, g);
    cnts[1] = lbound(g2s, N_SITES, g+1) - lbound(g2s, N_SITES, g);
  }
  __syncthreads();
  float invb = 1.f / fmaxf((float)cnts[0], 1.f);
  float invs = 1.f / fmaxf((float)cnts[1], 1.f);
  xb[lane]   = bonds_g[(size_t)g*64 + lane] * invb;
  xsit[lane] = sites_g[(size_t)g*64 + lane] * invs;
  __syncthreads();
  {
    float a = statec_stu[(size_t)g*64 + lane];
    layerR<64,64,1,64>(W1a, xb,   &a, lane);
    layerR<64,64,1,64>(W1b, xsit, &a, lane);
    hsx[lane] = fmaxf(a, 0.f);
  }
  __syncthreads();
  {
    int j = lane & 31;
    float a = B2s[j];
    layerR<64,32,1,64>(W2, hsx, &a, j);
    if (lane < 32) h2x[lane] = fmaxf(a, 0.f);
  }
  __syncthreads();
  {
    float a = B3s[lane];
    layerR<32,64,1,32>(W3, h2x, &a, lane);
    out_states[(size_t)g*64 + lane] = fmaxf(a, 0.f) + states2[(size_t)g*64 + lane];
  }
}

// ---------- launch ----------
extern "C" void kernel_launch(void* const* d_in, const int* in_sizes, int n_in,
                              void* d_out, int out_size, void* d_ws, size_t ws_size,
                              hipStream_t stream)
{
  const float* sites   = (const float*)d_in[0];
  const float* bonds   = (const float*)d_in[1];
  const float* states  = (const float*)d_in[2];
  const float* w_sites1 = (const float*)d_in[3];  const float* b_sites1 = (const float*)d_in[4];
  const float* w_sites2 = (const float*)d_in[5];  const float* b_sites2 = (const float*)d_in[6];
  const float* w_bonds1 = (const float*)d_in[7];  const float* b_bonds1 = (const float*)d_in[8];
  const float* w_bonds2 = (const float*)d_in[9];  const float* b_bonds2 = (const float*)d_in[10];
  const float* w_states1= (const float*)d_in[11]; const float* b_states1= (const float*)d_in[12];
  const float* w_states2= (const float*)d_in[13]; const float* b_states2= (const float*)d_in[14];
  const float* w_bu1 = (const float*)d_in[15]; const float* b_bu1 = (const float*)d_in[16];
  const float* w_bu2 = (const float*)d_in[17]; const float* b_bu2 = (const float*)d_in[18];
  const float* w_bu3 = (const float*)d_in[19]; const float* b_bu3 = (const float*)d_in[20];
  const float* w_su1 = (const float*)d_in[21]; const float* b_su1 = (const float*)d_in[22];
  const float* w_su2 = (const float*)d_in[23]; const float* b_su2 = (const float*)d_in[24];
  const float* w_su3 = (const float*)d_in[25]; const float* b_su3 = (const float*)d_in[26];
  const float* w_stu1= (const float*)d_in[27]; const float* b_stu1= (const float*)d_in[28];
  const float* w_stu2= (const float*)d_in[29]; const float* b_stu2= (const float*)d_in[30];
  const float* w_stu3= (const float*)d_in[31]; const float* b_stu3= (const float*)d_in[32];
  const int* idx1 = (const int*)d_in[33];
  const int* idx2 = (const int*)d_in[34];
  const int* g2s  = (const int*)d_in[35];
  const int* g2b  = (const int*)d_in[36];

  // d_ws usage: ~27.6 MB
  float* p = (float*)d_ws;
  float* bonds_pool = p;        p += (size_t)N_SITES*64;     // zeroed
  float* bonds_g    = p;        p += (size_t)N_GRAPHS*64;    // zeroed
  float* sites_g    = p;        p += (size_t)N_GRAPHS*64;    // zeroed
  int*   cnt_pool   = (int*)p;  p += N_SITES;                // zeroed
  float* states2    = p;        p += (size_t)N_GRAPHS*64;
  float* statec_bu  = p;        p += (size_t)N_GRAPHS*64;
  float* statec_su  = p;        p += (size_t)N_GRAPHS*64;
  float* statec_stu = p;        p += (size_t)N_GRAPHS*64;

  size_t zero_bytes = ((size_t)N_SITES*64 + 2*(size_t)N_GRAPHS*64 + (size_t)N_SITES) * 4;
  hipMemsetAsync(d_ws, 0, zero_bytes, stream);

  float* out_sites  = (float*)d_out;
  float* out_bonds  = out_sites + (size_t)N_SITES*64;
  float* out_states = out_bonds + (size_t)N_BONDS*64;
  float* sites2     = out_sites;   // fp32 sites2 staged in the sites output
                                   // region: written by sites_pre, gathered by
                                   // bond_kernel, read-then-overwritten in
                                   // place by site_kernel (each element only
                                   // by its owning thread).

  hipLaunchKernelGGL(prep_small_kernel, dim3(250), dim3(256), 0, stream,
      states, w_states1, b_states1, w_states2, b_states2,
      w_bu1, b_bu1, w_su1, b_su1, w_stu1, b_stu1,
      states2, statec_bu, statec_su, statec_stu);

  hipLaunchKernelGGL(sites_pre_kernel, dim3(1024), dim3(256), 0, stream,
      sites, w_sites1, b_sites1, w_sites2, b_sites2, sites2);

  // 12500 waves of 64 bonds, 16 waves/block -> 782 blocks
  hipLaunchKernelGGL(bond_kernel, dim3(782), dim3(1024), 0, stream,
      bonds, w_bonds1, b_bonds1, w_bonds2, b_bonds2,
      w_bu1, w_bu2, b_bu2, w_bu3, b_bu3,
      idx1, idx2, g2b, sites2, statec_bu,
      bonds_pool, cnt_pool, bonds_g, out_bonds);

  // 6250 waves of 16 sites, 8 waves/block -> 782 blocks
  hipLaunchKernelGGL(site_kernel, dim3(782), dim3(512), 0, stream,
      sites2, bonds_pool, cnt_pool, g2s, statec_su,
      w_su1, w_su2, b_su2, w_su3, b_su3,
      sites_g, out_sites);

  hipLaunchKernelGGL(state_kernel, dim3(1000), dim3(64), 0, stream,
      states2, bonds_g, sites_g, g2b, g2s,
      w_stu1, w_stu2, b_stu2, w_stu3, b_stu3,
      statec_stu, out_states);
}

// Round 3
// 2598.926 us; speedup vs baseline: 1.0055x; 1.0055x over previous
//
#include <hip/hip_runtime.h>

#define N_SITES  100000
#define N_BONDS  800000
#define N_GRAPHS 1000

// ---------- LDS staging helpers (fp32) ----------
template<int CNT>
__device__ __forceinline__ void stage_w(float* dst, const float* __restrict__ src, int tid, int nth){
  for (int i = tid; i < CNT; i += nth) dst[i] = src[i];
}
__device__ __forceinline__ void stage_b(float* dst, const float* __restrict__ src, int n, int tid){
  if (tid < n) dst[tid] = src[tid];
}

// acc[r] += sum_k x[r*XS + k] * W[k*N + j]
// W in LDS [K][N]: lane-consecutive reads (2-way bank alias = free).
// x in LDS, read as same-address float4 broadcasts (conflict-free).
template<int K, int N, int R, int XS>
__device__ __forceinline__ void layerR(const float* __restrict__ W,
                                       const float* __restrict__ x,
                                       float* __restrict__ acc, int j)
{
  #pragma unroll
  for (int k = 0; k < K; k += 4){
    float w0 = W[(k+0)*N + j];
    float w1 = W[(k+1)*N + j];
    float w2 = W[(k+2)*N + j];
    float w3 = W[(k+3)*N + j];
    #pragma unroll
    for (int r = 0; r < R; ++r){
      float4 xv = *(const float4*)(x + r*XS + k);
      acc[r] = fmaf(xv.x, w0, acc[r]);
      acc[r] = fmaf(xv.y, w1, acc[r]);
      acc[r] = fmaf(xv.z, w2, acc[r]);
      acc[r] = fmaf(xv.w, w3, acc[r]);
    }
  }
}

__device__ __forceinline__ int lbound(const int* __restrict__ a, int n, int v){
  int lo = 0, hi = n;
  while (lo < hi){ int m = (lo+hi) >> 1; if (a[m] < v) lo = m+1; else hi = m; }
  return lo;
}

// ---------- kernel 1: states path prep (1000 rows) ----------
__global__ __launch_bounds__(256) void prep_small_kernel(
    const float* __restrict__ states,
    const float* __restrict__ w1, const float* __restrict__ b1,
    const float* __restrict__ w2, const float* __restrict__ b2,
    const float* __restrict__ w_bu1, const float* __restrict__ b_bu1,
    const float* __restrict__ w_su1, const float* __restrict__ b_su1,
    const float* __restrict__ w_stu1, const float* __restrict__ b_stu1,
    float* __restrict__ states2, float* __restrict__ statec_bu,
    float* __restrict__ statec_su, float* __restrict__ statec_stu)
{
  __shared__ float W1[4096], W2[4096], WD[4096], WsuC[4096], WstuC[4096];
  __shared__ float B1[64], B2[64], Bbu[64], Bsu[64], Bstu[64];
  __shared__ alignas(16) float xs[4][64];
  __shared__ alignas(16) float hs[4][64];
  int tid = threadIdx.x;
  stage_w<4096>(W1,    w1,              tid, 256);
  stage_w<4096>(W2,    w2,              tid, 256);
  stage_w<4096>(WD,    w_bu1 + 192*64,  tid, 256);
  stage_w<4096>(WsuC,  w_su1 + 128*64,  tid, 256);
  stage_w<4096>(WstuC, w_stu1 + 128*64, tid, 256);
  stage_b(B1, b1, 64, tid);  stage_b(B2, b2, 64, tid);
  stage_b(Bbu, b_bu1, 64, tid); stage_b(Bsu, b_su1, 64, tid); stage_b(Bstu, b_stu1, 64, tid);
  __syncthreads();
  int w = tid >> 6, lane = tid & 63;
  int g = blockIdx.x*4 + w;                       // 250 blocks * 4 = exactly 1000
  xs[w][lane] = states[(size_t)g*64 + lane];
  float a = B1[lane];
  layerR<64,64,1,64>(W1, xs[w], &a, lane);
  hs[w][lane] = fmaxf(a, 0.f);
  a = B2[lane];
  layerR<64,64,1,64>(W2, hs[w], &a, lane);
  float s2 = fmaxf(a, 0.f);
  xs[w][lane] = s2;
  size_t o = (size_t)g*64 + lane;
  float abu = Bbu[lane], asu = Bsu[lane], astu = Bstu[lane];
  layerR<64,64,1,64>(WD,    xs[w], &abu,  lane);
  layerR<64,64,1,64>(WsuC,  xs[w], &asu,  lane);
  layerR<64,64,1,64>(WstuC, xs[w], &astu, lane);
  states2[o]    = s2;
  statec_bu[o]  = abu;
  statec_su[o]  = asu;
  statec_stu[o] = astu;
}

// ---------- kernel 2: sites pre-MLP (100000 rows) -> fp32 sites2 ----------
__global__ __launch_bounds__(256) void sites_pre_kernel(
    const float* __restrict__ sites,
    const float* __restrict__ w1, const float* __restrict__ b1,
    const float* __restrict__ w2, const float* __restrict__ b2,
    float* __restrict__ sites2)
{
  __shared__ float W1[4096], W2[4096];
  __shared__ float B1[64], B2[64];
  __shared__ alignas(16) float xs[4][4][64];
  __shared__ alignas(16) float hs[4][4][64];
  int tid = threadIdx.x;
  stage_w<4096>(W1, w1, tid, 256);
  stage_w<4096>(W2, w2, tid, 256);
  stage_b(B1, b1, 64, tid); stage_b(B2, b2, 64, tid);
  __syncthreads();
  int w = tid >> 6, lane = tid & 63;
  int wgid = blockIdx.x*4 + w;                     // 1024 blocks * 4 waves = 4096
  for (int n = 0; n < 7; ++n){                     // 7*4096 >= 25000 groups of 4 sites
    int G = n*4096 + wgid;
    if (G >= 25000) break;
    #pragma unroll
    for (int r = 0; r < 4; ++r)
      xs[w][r][lane] = sites[((size_t)(4*G + r))*64 + lane];
    {
      float a[4] = {B1[lane], B1[lane], B1[lane], B1[lane]};
      layerR<64,64,4,64>(W1, &xs[w][0][0], a, lane);
      #pragma unroll
      for (int r = 0; r < 4; ++r) hs[w][r][lane] = fmaxf(a[r], 0.f);
    }
    {
      float a[4] = {B2[lane], B2[lane], B2[lane], B2[lane]};
      layerR<64,64,4,64>(W2, &hs[w][0][0], a, lane);
      #pragma unroll
      for (int r = 0; r < 4; ++r)
        sites2[((size_t)(4*G + r))*64 + lane] = fmaxf(a[r], 0.f);
    }
  }
}

// ---------- kernel 3: bond kernel (fused bonds pre-MLP + gather + bond update) ----------
// 1024 threads = 16 waves share ONE copy of the 96 KiB of weights.
// LDS = 153 KiB -> hardware can fit only 1 block/CU = 4 waves/SIMD.
// __launch_bounds__(1024, 4): declare exactly those 4 waves/EU so the
// allocator gets the full 512/4 = 128 VGPR budget. Round-2 regression:
// without the 2nd arg the compiler squeezed to 64 VGPRs (an occupancy
// level LDS makes unreachable) and spilled ~2.4 GB/launch to scratch
// (FETCH 295MB->2.7GB, WRITE 428MB->2.9GB, VALUBusy stuck at 31%).
__global__ __launch_bounds__(1024, 4) void bond_kernel(
    const float* __restrict__ bonds,
    const float* __restrict__ wb1, const float* __restrict__ bb1,
    const float* __restrict__ wb2, const float* __restrict__ bb2,
    const float* __restrict__ w_bu1,
    const float* __restrict__ w_bu2, const float* __restrict__ b_bu2,
    const float* __restrict__ w_bu3, const float* __restrict__ b_bu3,
    const int* __restrict__ idx1, const int* __restrict__ idx2, const int* __restrict__ g2b,
    const float* __restrict__ sites2, const float* __restrict__ statec_bu,
    float* __restrict__ bonds_pool, int* __restrict__ cnt_pool, float* __restrict__ bonds_g,
    float* __restrict__ out_bonds)
{
  __shared__ float W1[4096], W2[4096], WA[4096], WB[4096], WC[4096];
  __shared__ float WU2[2048], WU3[2048];
  __shared__ float Bb1[64], Bb2[64], Bu2[32], Bu3[64];
  __shared__ alignas(16) float xs[16][4][64];   // bonds-in, then bonds2
  __shared__ alignas(16) float xg[16][4][64];   // scratch: s1 then s2
  __shared__ alignas(16) float hs[16][4][64];
  __shared__ alignas(16) float h2[16][4][32];
  int tid = threadIdx.x;
  stage_w<4096>(W1, wb1,            tid, 1024);
  stage_w<4096>(W2, wb2,            tid, 1024);
  stage_w<4096>(WA, w_bu1,          tid, 1024);
  stage_w<4096>(WB, w_bu1 + 64*64,  tid, 1024);
  stage_w<4096>(WC, w_bu1 + 128*64, tid, 1024);
  stage_w<2048>(WU2, w_bu2,         tid, 1024);
  stage_w<2048>(WU3, w_bu3,         tid, 1024);
  stage_b(Bb1, bb1, 64, tid); stage_b(Bb2, bb2, 64, tid);
  stage_b(Bu2, b_bu2, 32, tid); stage_b(Bu3, b_bu3, 64, tid);
  __syncthreads();
  int w = tid >> 6, lane = tid & 63;
  int ebase = blockIdx.x*1024 + w*64;   // wave owns 64 CONTIGUOUS bonds (g2b sorted)
  if (ebase >= N_BONDS) return;         // tail block: inactive waves exit after barrier
  float gacc = 0.f; int cur_g = -1;
  for (int it = 0; it < 16; ++it){
    int e0 = ebase + it*4;
    int i1a[4], i2a[4], gg[4];
    #pragma unroll
    for (int r = 0; r < 4; ++r){
      int e = e0 + r;
      i1a[r] = idx1[e]; i2a[r] = idx2[e]; gg[r] = g2b[e];
    }
    float vb[4], v1[4], v2[4];
    #pragma unroll
    for (int r = 0; r < 4; ++r){
      vb[r] = bonds[(size_t)(e0+r)*64 + lane];
      v1[r] = sites2[(size_t)i1a[r]*64 + lane];
      v2[r] = sites2[(size_t)i2a[r]*64 + lane];
    }
    #pragma unroll
    for (int r = 0; r < 4; ++r) xs[w][r][lane] = vb[r];
    // bonds pre-MLP layer 1
    {
      float a[4] = {Bb1[lane], Bb1[lane], Bb1[lane], Bb1[lane]};
      layerR<64,64,4,64>(W1, &xs[w][0][0], a, lane);
      #pragma unroll
      for (int r = 0; r < 4; ++r) hs[w][r][lane] = fmaxf(a[r], 0.f);
    }
    // bonds pre-MLP layer 2 -> bonds2 (residual), stash into xs
    float b2v[4];
    {
      float a[4] = {Bb2[lane], Bb2[lane], Bb2[lane], Bb2[lane]};
      layerR<64,64,4,64>(W2, &hs[w][0][0], a, lane);
      #pragma unroll
      for (int r = 0; r < 4; ++r) b2v[r] = fmaxf(a[r], 0.f);
    }
    #pragma unroll
    for (int r = 0; r < 4; ++r) xs[w][r][lane] = b2v[r];
    // bond-update fc1: A*s1 + B*s2 + C*bonds2 + (state slice incl. bias)
    {
      float a[4];
      #pragma unroll
      for (int r = 0; r < 4; ++r) a[r] = statec_bu[(size_t)gg[r]*64 + lane];
      #pragma unroll
      for (int r = 0; r < 4; ++r) xg[w][r][lane] = v1[r];
      layerR<64,64,4,64>(WA, &xg[w][0][0], a, lane);
      #pragma unroll
      for (int r = 0; r < 4; ++r) xg[w][r][lane] = v2[r];   // wave-ordered after WA reads
      layerR<64,64,4,64>(WB, &xg[w][0][0], a, lane);
      layerR<64,64,4,64>(WC, &xs[w][0][0], a, lane);
      #pragma unroll
      for (int r = 0; r < 4; ++r) hs[w][r][lane] = fmaxf(a[r], 0.f);
    }
    // bond-update fc2 (64 -> 32); all lanes compute j=lane&31, low lanes write
    {
      int j = lane & 31;
      float a[4] = {Bu2[j], Bu2[j], Bu2[j], Bu2[j]};
      layerR<64,32,4,64>(WU2, &hs[w][0][0], a, j);
      if (lane < 32){
        #pragma unroll
        for (int r = 0; r < 4; ++r) h2[w][r][lane] = fmaxf(a[r], 0.f);
      }
    }
    // bond-update fc3 (32 -> 64) + epilogue
    {
      float a[4] = {Bu3[lane], Bu3[lane], Bu3[lane], Bu3[lane]};
      layerR<32,64,4,32>(WU3, &h2[w][0][0], a, lane);
      #pragma unroll
      for (int r = 0; r < 4; ++r){
        float bnew = fmaxf(a[r], 0.f);
        int e = e0 + r;
        out_bonds[(size_t)e*64 + lane] = bnew + b2v[r];
        atomicAdd(&bonds_pool[(size_t)i1a[r]*64 + lane], bnew);
        if (lane == 0) atomicAdd(&cnt_pool[i1a[r]], 1);
        if (gg[r] != cur_g){
          if (cur_g >= 0) atomicAdd(&bonds_g[(size_t)cur_g*64 + lane], gacc);
          cur_g = gg[r]; gacc = 0.f;
        }
        gacc += bnew;
      }
    }
  }
  if (cur_g >= 0) atomicAdd(&bonds_g[(size_t)cur_g*64 + lane], gacc);
}

// ---------- kernel 4: site update (100000 rows) ----------
__global__ __launch_bounds__(512, 4) void site_kernel(
    const float* __restrict__ sites2, const float* __restrict__ bonds_pool, const int* __restrict__ cnt_pool,
    const int* __restrict__ g2s, const float* __restrict__ statec_su,
    const float* __restrict__ w_su1, const float* __restrict__ w_su2, const float* __restrict__ b_su2,
    const float* __restrict__ w_su3, const float* __restrict__ b_su3,
    float* __restrict__ sites_g, float* __restrict__ out_sites)
{
  __shared__ float W1a[4096], W1b[4096], W2[2048], W3[2048];
  __shared__ float B2s[32], B3s[64];
  __shared__ alignas(16) float xg[8][4][64];   // scratch: pooled bonds, then sites2
  __shared__ alignas(16) float hs[8][4][64];
  __shared__ alignas(16) float h2[8][4][32];
  int tid = threadIdx.x;
  stage_w<4096>(W1a, w_su1,         tid, 512);
  stage_w<4096>(W1b, w_su1 + 64*64, tid, 512);
  stage_w<2048>(W2,  w_su2,         tid, 512);
  stage_w<2048>(W3,  w_su3,         tid, 512);
  stage_b(B2s, b_su2, 32, tid); stage_b(B3s, b_su3, 64, tid);
  __syncthreads();
  int w = tid >> 6, lane = tid & 63;
  int sbase = (blockIdx.x*8 + w)*16;    // contiguous sites per wave (g2s sorted)
  if (sbase >= N_SITES) return;
  float gacc = 0.f; int cur_g = -1;
  for (int it = 0; it < 4; ++it){
    int s0 = sbase + it*4;
    int gg[4]; float s2v[4], pv[4];
    #pragma unroll
    for (int r = 0; r < 4; ++r){
      int s = s0 + r;
      gg[r] = g2s[s];
      float inv = 1.f / fmaxf((float)cnt_pool[s], 1.f);
      pv[r]  = bonds_pool[(size_t)s*64 + lane] * inv;
      s2v[r] = sites2[(size_t)s*64 + lane];
    }
    {
      float a[4];
      #pragma unroll
      for (int r = 0; r < 4; ++r) a[r] = statec_su[(size_t)gg[r]*64 + lane];
      #pragma unroll
      for (int r = 0; r < 4; ++r) xg[w][r][lane] = pv[r];
      layerR<64,64,4,64>(W1a, &xg[w][0][0], a, lane);
      #pragma unroll
      for (int r = 0; r < 4; ++r) xg[w][r][lane] = s2v[r];  // wave-ordered after W1a reads
      layerR<64,64,4,64>(W1b, &xg[w][0][0], a, lane);
      #pragma unroll
      for (int r = 0; r < 4; ++r) hs[w][r][lane] = fmaxf(a[r], 0.f);
    }
    {
      int j = lane & 31;
      float a[4] = {B2s[j], B2s[j], B2s[j], B2s[j]};
      layerR<64,32,4,64>(W2, &hs[w][0][0], a, j);
      if (lane < 32){
        #pragma unroll
        for (int r = 0; r < 4; ++r) h2[w][r][lane] = fmaxf(a[r], 0.f);
      }
    }
    {
      float a[4] = {B3s[lane], B3s[lane], B3s[lane], B3s[lane]};
      layerR<32,64,4,32>(W3, &h2[w][0][0], a, lane);
      #pragma unroll
      for (int r = 0; r < 4; ++r){
        int s = s0 + r;
        float snew = fmaxf(a[r], 0.f);
        out_sites[(size_t)s*64 + lane] = snew + s2v[r];
        if (gg[r] != cur_g){
          if (cur_g >= 0) atomicAdd(&sites_g[(size_t)cur_g*64 + lane], gacc);
          cur_g = gg[r]; gacc = 0.f;
        }
        gacc += snew;
      }
    }
  }
  if (cur_g >= 0) atomicAdd(&sites_g[(size_t)cur_g*64 + lane], gacc);
}

// ---------- kernel 5: state update (1000 graphs, one wave each) ----------
// Barriers REQUIRED around cooperative staging (round-1 failure: per-lane
// alias analysis can't see lane->lane staging deps).
__global__ __launch_bounds__(64) void state_kernel(
    const float* __restrict__ states2, const float* __restrict__ bonds_g, const float* __restrict__ sites_g,
    const int* __restrict__ g2b, const int* __restrict__ g2s,
    const float* __restrict__ w_stu1, const float* __restrict__ w_stu2, const float* __restrict__ b_stu2,
    const float* __restrict__ w_stu3, const float* __restrict__ b_stu3,
    const float* __restrict__ statec_stu, float* __restrict__ out_states)
{
  __shared__ float W1a[4096], W1b[4096], W2[2048], W3[2048];
  __shared__ float B2s[32], B3s[64];
  __shared__ alignas(16) float xb[64], xsit[64], hsx[64], h2x[32];
  __shared__ int cnts[2];
  int lane = threadIdx.x; int g = blockIdx.x;
  stage_w<4096>(W1a, w_stu1,         lane, 64);
  stage_w<4096>(W1b, w_stu1 + 64*64, lane, 64);
  stage_w<2048>(W2,  w_stu2,         lane, 64);
  stage_w<2048>(W3,  w_stu3,         lane, 64);
  stage_b(B2s, b_stu2, 32, lane); stage_b(B3s, b_stu3, 64, lane);
  if (lane == 0){
    cnts[0] = lbound(g2b, N_BONDS, g+1) - lbound(g2b, N_BONDS, g);
    cnts[1] = lbound(g2s, N_SITES, g+1) - lbound(g2s, N_SITES, g);
  }
  __syncthreads();
  float invb = 1.f / fmaxf((float)cnts[0], 1.f);
  float invs = 1.f / fmaxf((float)cnts[1], 1.f);
  xb[lane]   = bonds_g[(size_t)g*64 + lane] * invb;
  xsit[lane] = sites_g[(size_t)g*64 + lane] * invs;
  __syncthreads();
  {
    float a = statec_stu[(size_t)g*64 + lane];
    layerR<64,64,1,64>(W1a, xb,   &a, lane);
    layerR<64,64,1,64>(W1b, xsit, &a, lane);
    hsx[lane] = fmaxf(a, 0.f);
  }
  __syncthreads();
  {
    int j = lane & 31;
    float a = B2s[j];
    layerR<64,32,1,64>(W2, hsx, &a, j);
    if (lane < 32) h2x[lane] = fmaxf(a, 0.f);
  }
  __syncthreads();
  {
    float a = B3s[lane];
    layerR<32,64,1,32>(W3, h2x, &a, lane);
    out_states[(size_t)g*64 + lane] = fmaxf(a, 0.f) + states2[(size_t)g*64 + lane];
  }
}

// ---------- launch ----------
extern "C" void kernel_launch(void* const* d_in, const int* in_sizes, int n_in,
                              void* d_out, int out_size, void* d_ws, size_t ws_size,
                              hipStream_t stream)
{
  const float* sites   = (const float*)d_in[0];
  const float* bonds   = (const float*)d_in[1];
  const float* states  = (const float*)d_in[2];
  const float* w_sites1 = (const float*)d_in[3];  const float* b_sites1 = (const float*)d_in[4];
  const float* w_sites2 = (const float*)d_in[5];  const float* b_sites2 = (const float*)d_in[6];
  const float* w_bonds1 = (const float*)d_in[7];  const float* b_bonds1 = (const float*)d_in[8];
  const float* w_bonds2 = (const float*)d_in[9];  const float* b_bonds2 = (const float*)d_in[10];
  const float* w_states1= (const float*)d_in[11]; const float* b_states1= (const float*)d_in[12];
  const float* w_states2= (const float*)d_in[13]; const float* b_states2= (const float*)d_in[14];
  const float* w_bu1 = (const float*)d_in[15]; const float* b_bu1 = (const float*)d_in[16];
  const float* w_bu2 = (const float*)d_in[17]; const float* b_bu2 = (const float*)d_in[18];
  const float* w_bu3 = (const float*)d_in[19]; const float* b_bu3 = (const float*)d_in[20];
  const float* w_su1 = (const float*)d_in[21]; const float* b_su1 = (const float*)d_in[22];
  const float* w_su2 = (const float*)d_in[23]; const float* b_su2 = (const float*)d_in[24];
  const float* w_su3 = (const float*)d_in[25]; const float* b_su3 = (const float*)d_in[26];
  const float* w_stu1= (const float*)d_in[27]; const float* b_stu1= (const float*)d_in[28];
  const float* w_stu2= (const float*)d_in[29]; const float* b_stu2= (const float*)d_in[30];
  const float* w_stu3= (const float*)d_in[31]; const float* b_stu3= (const float*)d_in[32];
  const int* idx1 = (const int*)d_in[33];
  const int* idx2 = (const int*)d_in[34];
  const int* g2s  = (const int*)d_in[35];
  const int* g2b  = (const int*)d_in[36];

  // d_ws usage: ~27.6 MB
  float* p = (float*)d_ws;
  float* bonds_pool = p;        p += (size_t)N_SITES*64;     // zeroed
  float* bonds_g    = p;        p += (size_t)N_GRAPHS*64;    // zeroed
  float* sites_g    = p;        p += (size_t)N_GRAPHS*64;    // zeroed
  int*   cnt_pool   = (int*)p;  p += N_SITES;                // zeroed
  float* states2    = p;        p += (size_t)N_GRAPHS*64;
  float* statec_bu  = p;        p += (size_t)N_GRAPHS*64;
  float* statec_su  = p;        p += (size_t)N_GRAPHS*64;
  float* statec_stu = p;        p += (size_t)N_GRAPHS*64;

  size_t zero_bytes = ((size_t)N_SITES*64 + 2*(size_t)N_GRAPHS*64 + (size_t)N_SITES) * 4;
  hipMemsetAsync(d_ws, 0, zero_bytes, stream);

  float* out_sites  = (float*)d_out;
  float* out_bonds  = out_sites + (size_t)N_SITES*64;
  float* out_states = out_bonds + (size_t)N_BONDS*64;
  float* sites2     = out_sites;   // fp32 sites2 staged in the sites output
                                   // region: written by sites_pre, gathered by
                                   // bond_kernel, read-then-overwritten in
                                   // place by site_kernel (each element only
                                   // by its owning thread).

  hipLaunchKernelGGL(prep_small_kernel, dim3(250), dim3(256), 0, stream,
      states, w_states1, b_states1, w_states2, b_states2,
      w_bu1, b_bu1, w_su1, b_su1, w_stu1, b_stu1,
      states2, statec_bu, statec_su, statec_stu);

  hipLaunchKernelGGL(sites_pre_kernel, dim3(1024), dim3(256), 0, stream,
      sites, w_sites1, b_sites1, w_sites2, b_sites2, sites2);

  // 12500 waves of 64 bonds, 16 waves/block -> 782 blocks
  hipLaunchKernelGGL(bond_kernel, dim3(782), dim3(1024), 0, stream,
      bonds, w_bonds1, b_bonds1, w_bonds2, b_bonds2,
      w_bu1, w_bu2, b_bu2, w_bu3, b_bu3,
      idx1, idx2, g2b, sites2, statec_bu,
      bonds_pool, cnt_pool, bonds_g, out_bonds);

  // 6250 waves of 16 sites, 8 waves/block -> 782 blocks
  hipLaunchKernelGGL(site_kernel, dim3(782), dim3(512), 0, stream,
      sites2, bonds_pool, cnt_pool, g2s, statec_su,
      w_su1, w_su2, b_su2, w_su3, b_su3,
      sites_g, out_sites);

  hipLaunchKernelGGL(state_kernel, dim3(1000), dim3(64), 0, stream,
      states2, bonds_g, sites_g, g2b, g2s,
      w_stu1, w_stu2, b_stu2, w_stu3, b_stu3,
      statec_stu, out_states);
}

// Round 4
// 2595.565 us; speedup vs baseline: 1.0068x; 1.0013x over previous
//
#include <hip/hip_runtime.h>

#define N_SITES  100000
#define N_BONDS  800000
#define N_GRAPHS 1000

// ---------- LDS staging helpers (fp32) ----------
template<int CNT>
__device__ __forceinline__ void stage_w(float* dst, const float* __restrict__ src, int tid, int nth){
  for (int i = tid; i < CNT; i += nth) dst[i] = src[i];
}
__device__ __forceinline__ void stage_b(float* dst, const float* __restrict__ src, int n, int tid){
  if (tid < n) dst[tid] = src[tid];
}

// acc[r] += sum_k x[r*XS + k] * W[k*N + j]
// W in LDS [K][N]: lane-consecutive reads (2-way bank alias = free).
// x in LDS, read as same-address float4 broadcasts (conflict-free).
template<int K, int N, int R, int XS>
__device__ __forceinline__ void layerR(const float* __restrict__ W,
                                       const float* __restrict__ x,
                                       float* __restrict__ acc, int j)
{
  #pragma unroll
  for (int k = 0; k < K; k += 4){
    float w0 = W[(k+0)*N + j];
    float w1 = W[(k+1)*N + j];
    float w2 = W[(k+2)*N + j];
    float w3 = W[(k+3)*N + j];
    #pragma unroll
    for (int r = 0; r < R; ++r){
      float4 xv = *(const float4*)(x + r*XS + k);
      acc[r] = fmaf(xv.x, w0, acc[r]);
      acc[r] = fmaf(xv.y, w1, acc[r]);
      acc[r] = fmaf(xv.z, w2, acc[r]);
      acc[r] = fmaf(xv.w, w3, acc[r]);
    }
  }
}

__device__ __forceinline__ int lbound(const int* __restrict__ a, int n, int v){
  int lo = 0, hi = n;
  while (lo < hi){ int m = (lo+hi) >> 1; if (a[m] < v) lo = m+1; else hi = m; }
  return lo;
}

// ---------- kernel 1: states path prep (1000 rows) ----------
__global__ __launch_bounds__(256) void prep_small_kernel(
    const float* __restrict__ states,
    const float* __restrict__ w1, const float* __restrict__ b1,
    const float* __restrict__ w2, const float* __restrict__ b2,
    const float* __restrict__ w_bu1, const float* __restrict__ b_bu1,
    const float* __restrict__ w_su1, const float* __restrict__ b_su1,
    const float* __restrict__ w_stu1, const float* __restrict__ b_stu1,
    float* __restrict__ states2, float* __restrict__ statec_bu,
    float* __restrict__ statec_su, float* __restrict__ statec_stu)
{
  __shared__ float W1[4096], W2[4096], WD[4096], WsuC[4096], WstuC[4096];
  __shared__ float B1[64], B2[64], Bbu[64], Bsu[64], Bstu[64];
  __shared__ alignas(16) float xs[4][64];
  __shared__ alignas(16) float hs[4][64];
  int tid = threadIdx.x;
  stage_w<4096>(W1,    w1,              tid, 256);
  stage_w<4096>(W2,    w2,              tid, 256);
  stage_w<4096>(WD,    w_bu1 + 192*64,  tid, 256);
  stage_w<4096>(WsuC,  w_su1 + 128*64,  tid, 256);
  stage_w<4096>(WstuC, w_stu1 + 128*64, tid, 256);
  stage_b(B1, b1, 64, tid);  stage_b(B2, b2, 64, tid);
  stage_b(Bbu, b_bu1, 64, tid); stage_b(Bsu, b_su1, 64, tid); stage_b(Bstu, b_stu1, 64, tid);
  __syncthreads();
  int w = tid >> 6, lane = tid & 63;
  int g = blockIdx.x*4 + w;                       // 250 blocks * 4 = exactly 1000
  xs[w][lane] = states[(size_t)g*64 + lane];
  float a = B1[lane];
  layerR<64,64,1,64>(W1, xs[w], &a, lane);
  hs[w][lane] = fmaxf(a, 0.f);
  a = B2[lane];
  layerR<64,64,1,64>(W2, hs[w], &a, lane);
  float s2 = fmaxf(a, 0.f);
  xs[w][lane] = s2;
  size_t o = (size_t)g*64 + lane;
  float abu = Bbu[lane], asu = Bsu[lane], astu = Bstu[lane];
  layerR<64,64,1,64>(WD,    xs[w], &abu,  lane);
  layerR<64,64,1,64>(WsuC,  xs[w], &asu,  lane);
  layerR<64,64,1,64>(WstuC, xs[w], &astu, lane);
  states2[o]    = s2;
  statec_bu[o]  = abu;
  statec_su[o]  = asu;
  statec_stu[o] = astu;
}

// ---------- kernel 2: sites pre-MLP (100000 rows) -> fp32 sites2 ----------
__global__ __launch_bounds__(256) void sites_pre_kernel(
    const float* __restrict__ sites,
    const float* __restrict__ w1, const float* __restrict__ b1,
    const float* __restrict__ w2, const float* __restrict__ b2,
    float* __restrict__ sites2)
{
  __shared__ float W1[4096], W2[4096];
  __shared__ float B1[64], B2[64];
  __shared__ alignas(16) float xs[4][4][64];
  __shared__ alignas(16) float hs[4][4][64];
  int tid = threadIdx.x;
  stage_w<4096>(W1, w1, tid, 256);
  stage_w<4096>(W2, w2, tid, 256);
  stage_b(B1, b1, 64, tid); stage_b(B2, b2, 64, tid);
  __syncthreads();
  int w = tid >> 6, lane = tid & 63;
  int wgid = blockIdx.x*4 + w;                     // 1024 blocks * 4 waves = 4096
  for (int n = 0; n < 7; ++n){                     // 7*4096 >= 25000 groups of 4 sites
    int G = n*4096 + wgid;
    if (G >= 25000) break;
    #pragma unroll
    for (int r = 0; r < 4; ++r)
      xs[w][r][lane] = sites[((size_t)(4*G + r))*64 + lane];
    {
      float a[4] = {B1[lane], B1[lane], B1[lane], B1[lane]};
      layerR<64,64,4,64>(W1, &xs[w][0][0], a, lane);
      #pragma unroll
      for (int r = 0; r < 4; ++r) hs[w][r][lane] = fmaxf(a[r], 0.f);
    }
    {
      float a[4] = {B2[lane], B2[lane], B2[lane], B2[lane]};
      layerR<64,64,4,64>(W2, &hs[w][0][0], a, lane);
      #pragma unroll
      for (int r = 0; r < 4; ++r)
        sites2[((size_t)(4*G + r))*64 + lane] = fmaxf(a[r], 0.f);
    }
  }
}

// ---------- kernel 3: bond kernel (fused bonds pre-MLP + gather + bond update) ----------
// 1024 threads = 16 waves share ONE copy of the 96 KiB of weights.
// LDS = 153 KiB -> hardware fits exactly 1 block/CU = 4 waves/SIMD.
// amdgpu_waves_per_eu(4,4): pin the allocator's occupancy target to the
// 4 waves/SIMD that LDS actually permits -> VGPR budget 512/4 = 128.
// (launch_bounds(1024,4) was a NO-OP in round 3: it only sets a MINIMUM
// waves/EU; the heuristic still targeted 8 waves/EU -> 64 VGPRs -> ~2.4GB
// of scratch spill traffic per launch. min=max=4 removes that freedom.)
__global__ __launch_bounds__(1024)
__attribute__((amdgpu_waves_per_eu(4, 4)))
void bond_kernel(
    const float* __restrict__ bonds,
    const float* __restrict__ wb1, const float* __restrict__ bb1,
    const float* __restrict__ wb2, const float* __restrict__ bb2,
    const float* __restrict__ w_bu1,
    const float* __restrict__ w_bu2, const float* __restrict__ b_bu2,
    const float* __restrict__ w_bu3, const float* __restrict__ b_bu3,
    const int* __restrict__ idx1, const int* __restrict__ idx2, const int* __restrict__ g2b,
    const float* __restrict__ sites2, const float* __restrict__ statec_bu,
    float* __restrict__ bonds_pool, int* __restrict__ cnt_pool, float* __restrict__ bonds_g,
    float* __restrict__ out_bonds)
{
  __shared__ float W1[4096], W2[4096], WA[4096], WB[4096], WC[4096];
  __shared__ float WU2[2048], WU3[2048];
  __shared__ float Bb1[64], Bb2[64], Bu2[32], Bu3[64];
  __shared__ alignas(16) float xs[16][4][64];   // bonds-in, then bonds2
  __shared__ alignas(16) float xg[16][4][64];   // scratch: s1 then s2
  __shared__ alignas(16) float hs[16][4][64];
  __shared__ alignas(16) float h2[16][4][32];
  int tid = threadIdx.x;
  stage_w<4096>(W1, wb1,            tid, 1024);
  stage_w<4096>(W2, wb2,            tid, 1024);
  stage_w<4096>(WA, w_bu1,          tid, 1024);
  stage_w<4096>(WB, w_bu1 + 64*64,  tid, 1024);
  stage_w<4096>(WC, w_bu1 + 128*64, tid, 1024);
  stage_w<2048>(WU2, w_bu2,         tid, 1024);
  stage_w<2048>(WU3, w_bu3,         tid, 1024);
  stage_b(Bb1, bb1, 64, tid); stage_b(Bb2, bb2, 64, tid);
  stage_b(Bu2, b_bu2, 32, tid); stage_b(Bu3, b_bu3, 64, tid);
  __syncthreads();
  int w = tid >> 6, lane = tid & 63;
  int ebase = blockIdx.x*1024 + w*64;   // wave owns 64 CONTIGUOUS bonds (g2b sorted)
  if (ebase >= N_BONDS) return;         // tail block: inactive waves exit after barrier
  float gacc = 0.f; int cur_g = -1;
  for (int it = 0; it < 16; ++it){
    int e0 = ebase + it*4;
    int i1a[4], i2a[4], gg[4];
    #pragma unroll
    for (int r = 0; r < 4; ++r){
      int e = e0 + r;
      i1a[r] = idx1[e]; i2a[r] = idx2[e]; gg[r] = g2b[e];
    }
    float vb[4], v1[4], v2[4];
    #pragma unroll
    for (int r = 0; r < 4; ++r){
      vb[r] = bonds[(size_t)(e0+r)*64 + lane];
      v1[r] = sites2[(size_t)i1a[r]*64 + lane];
      v2[r] = sites2[(size_t)i2a[r]*64 + lane];
    }
    #pragma unroll
    for (int r = 0; r < 4; ++r) xs[w][r][lane] = vb[r];
    // bonds pre-MLP layer 1
    {
      float a[4] = {Bb1[lane], Bb1[lane], Bb1[lane], Bb1[lane]};
      layerR<64,64,4,64>(W1, &xs[w][0][0], a, lane);
      #pragma unroll
      for (int r = 0; r < 4; ++r) hs[w][r][lane] = fmaxf(a[r], 0.f);
    }
    // bonds pre-MLP layer 2 -> bonds2 (residual), stash into xs
    float b2v[4];
    {
      float a[4] = {Bb2[lane], Bb2[lane], Bb2[lane], Bb2[lane]};
      layerR<64,64,4,64>(W2, &hs[w][0][0], a, lane);
      #pragma unroll
      for (int r = 0; r < 4; ++r) b2v[r] = fmaxf(a[r], 0.f);
    }
    #pragma unroll
    for (int r = 0; r < 4; ++r) xs[w][r][lane] = b2v[r];
    // bond-update fc1: A*s1 + B*s2 + C*bonds2 + (state slice incl. bias)
    {
      float a[4];
      #pragma unroll
      for (int r = 0; r < 4; ++r) a[r] = statec_bu[(size_t)gg[r]*64 + lane];
      #pragma unroll
      for (int r = 0; r < 4; ++r) xg[w][r][lane] = v1[r];
      layerR<64,64,4,64>(WA, &xg[w][0][0], a, lane);
      #pragma unroll
      for (int r = 0; r < 4; ++r) xg[w][r][lane] = v2[r];   // wave-ordered after WA reads
      layerR<64,64,4,64>(WB, &xg[w][0][0], a, lane);
      layerR<64,64,4,64>(WC, &xs[w][0][0], a, lane);
      #pragma unroll
      for (int r = 0; r < 4; ++r) hs[w][r][lane] = fmaxf(a[r], 0.f);
    }
    // bond-update fc2 (64 -> 32); all lanes compute j=lane&31, low lanes write
    {
      int j = lane & 31;
      float a[4] = {Bu2[j], Bu2[j], Bu2[j], Bu2[j]};
      layerR<64,32,4,64>(WU2, &hs[w][0][0], a, j);
      if (lane < 32){
        #pragma unroll
        for (int r = 0; r < 4; ++r) h2[w][r][lane] = fmaxf(a[r], 0.f);
      }
    }
    // bond-update fc3 (32 -> 64) + epilogue
    {
      float a[4] = {Bu3[lane], Bu3[lane], Bu3[lane], Bu3[lane]};
      layerR<32,64,4,32>(WU3, &h2[w][0][0], a, lane);
      #pragma unroll
      for (int r = 0; r < 4; ++r){
        float bnew = fmaxf(a[r], 0.f);
        int e = e0 + r;
        out_bonds[(size_t)e*64 + lane] = bnew + b2v[r];
        atomicAdd(&bonds_pool[(size_t)i1a[r]*64 + lane], bnew);
        if (lane == 0) atomicAdd(&cnt_pool[i1a[r]], 1);
        if (gg[r] != cur_g){
          if (cur_g >= 0) atomicAdd(&bonds_g[(size_t)cur_g*64 + lane], gacc);
          cur_g = gg[r]; gacc = 0.f;
        }
        gacc += bnew;
      }
    }
  }
  if (cur_g >= 0) atomicAdd(&bonds_g[(size_t)cur_g*64 + lane], gacc);
}

// ---------- kernel 4: site update (100000 rows) ----------
// 512 threads = 8 waves; LDS 68.4 KiB -> 2 blocks/CU = 4 waves/SIMD.
// Same allocator pinning as bond_kernel: min=max=4 waves/EU -> 128 VGPRs.
__global__ __launch_bounds__(512)
__attribute__((amdgpu_waves_per_eu(4, 4)))
void site_kernel(
    const float* __restrict__ sites2, const float* __restrict__ bonds_pool, const int* __restrict__ cnt_pool,
    const int* __restrict__ g2s, const float* __restrict__ statec_su,
    const float* __restrict__ w_su1, const float* __restrict__ w_su2, const float* __restrict__ b_su2,
    const float* __restrict__ w_su3, const float* __restrict__ b_su3,
    float* __restrict__ sites_g, float* __restrict__ out_sites)
{
  __shared__ float W1a[4096], W1b[4096], W2[2048], W3[2048];
  __shared__ float B2s[32], B3s[64];
  __shared__ alignas(16) float xg[8][4][64];   // scratch: pooled bonds, then sites2
  __shared__ alignas(16) float hs[8][4][64];
  __shared__ alignas(16) float h2[8][4][32];
  int tid = threadIdx.x;
  stage_w<4096>(W1a, w_su1,         tid, 512);
  stage_w<4096>(W1b, w_su1 + 64*64, tid, 512);
  stage_w<2048>(W2,  w_su2,         tid, 512);
  stage_w<2048>(W3,  w_su3,         tid, 512);
  stage_b(B2s, b_su2, 32, tid); stage_b(B3s, b_su3, 64, tid);
  __syncthreads();
  int w = tid >> 6, lane = tid & 63;
  int sbase = (blockIdx.x*8 + w)*16;    // contiguous sites per wave (g2s sorted)
  if (sbase >= N_SITES) return;
  float gacc = 0.f; int cur_g = -1;
  for (int it = 0; it < 4; ++it){
    int s0 = sbase + it*4;
    int gg[4]; float s2v[4], pv[4];
    #pragma unroll
    for (int r = 0; r < 4; ++r){
      int s = s0 + r;
      gg[r] = g2s[s];
      float inv = 1.f / fmaxf((float)cnt_pool[s], 1.f);
      pv[r]  = bonds_pool[(size_t)s*64 + lane] * inv;
      s2v[r] = sites2[(size_t)s*64 + lane];
    }
    {
      float a[4];
      #pragma unroll
      for (int r = 0; r < 4; ++r) a[r] = statec_su[(size_t)gg[r]*64 + lane];
      #pragma unroll
      for (int r = 0; r < 4; ++r) xg[w][r][lane] = pv[r];
      layerR<64,64,4,64>(W1a, &xg[w][0][0], a, lane);
      #pragma unroll
      for (int r = 0; r < 4; ++r) xg[w][r][lane] = s2v[r];  // wave-ordered after W1a reads
      layerR<64,64,4,64>(W1b, &xg[w][0][0], a, lane);
      #pragma unroll
      for (int r = 0; r < 4; ++r) hs[w][r][lane] = fmaxf(a[r], 0.f);
    }
    {
      int j = lane & 31;
      float a[4] = {B2s[j], B2s[j], B2s[j], B2s[j]};
      layerR<64,32,4,64>(W2, &hs[w][0][0], a, j);
      if (lane < 32){
        #pragma unroll
        for (int r = 0; r < 4; ++r) h2[w][r][lane] = fmaxf(a[r], 0.f);
      }
    }
    {
      float a[4] = {B3s[lane], B3s[lane], B3s[lane], B3s[lane]};
      layerR<32,64,4,32>(W3, &h2[w][0][0], a, lane);
      #pragma unroll
      for (int r = 0; r < 4; ++r){
        int s = s0 + r;
        float snew = fmaxf(a[r], 0.f);
        out_sites[(size_t)s*64 + lane] = snew + s2v[r];
        if (gg[r] != cur_g){
          if (cur_g >= 0) atomicAdd(&sites_g[(size_t)cur_g*64 + lane], gacc);
          cur_g = gg[r]; gacc = 0.f;
        }
        gacc += snew;
      }
    }
  }
  if (cur_g >= 0) atomicAdd(&sites_g[(size_t)cur_g*64 + lane], gacc);
}

// ---------- kernel 5: state update (1000 graphs, one wave each) ----------
// Barriers REQUIRED around cooperative staging (round-1 failure: per-lane
// alias analysis can't see lane->lane staging deps).
__global__ __launch_bounds__(64) void state_kernel(
    const float* __restrict__ states2, const float* __restrict__ bonds_g, const float* __restrict__ sites_g,
    const int* __restrict__ g2b, const int* __restrict__ g2s,
    const float* __restrict__ w_stu1, const float* __restrict__ w_stu2, const float* __restrict__ b_stu2,
    const float* __restrict__ w_stu3, const float* __restrict__ b_stu3,
    const float* __restrict__ statec_stu, float* __restrict__ out_states)
{
  __shared__ float W1a[4096], W1b[4096], W2[2048], W3[2048];
  __shared__ float B2s[32], B3s[64];
  __shared__ alignas(16) float xb[64], xsit[64], hsx[64], h2x[32];
  __shared__ int cnts[2];
  int lane = threadIdx.x; int g = blockIdx.x;
  stage_w<4096>(W1a, w_stu1,         lane, 64);
  stage_w<4096>(W1b, w_stu1 + 64*64, lane, 64);
  stage_w<2048>(W2,  w_stu2,         lane, 64);
  stage_w<2048>(W3,  w_stu3,         lane, 64);
  stage_b(B2s, b_stu2, 32, lane); stage_b(B3s, b_stu3, 64, lane);
  if (lane == 0){
    cnts[0] = lbound(g2b, N_BONDS, g+1) - lbound(g2b, N_BONDS, g);
    cnts[1] = lbound(g2s, N_SITES, g+1) - lbound(g2s, N_SITES, g);
  }
  __syncthreads();
  float invb = 1.f / fmaxf((float)cnts[0], 1.f);
  float invs = 1.f / fmaxf((float)cnts[1], 1.f);
  xb[lane]   = bonds_g[(size_t)g*64 + lane] * invb;
  xsit[lane] = sites_g[(size_t)g*64 + lane] * invs;
  __syncthreads();
  {
    float a = statec_stu[(size_t)g*64 + lane];
    layerR<64,64,1,64>(W1a, xb,   &a, lane);
    layerR<64,64,1,64>(W1b, xsit, &a, lane);
    hsx[lane] = fmaxf(a, 0.f);
  }
  __syncthreads();
  {
    int j = lane & 31;
    float a = B2s[j];
    layerR<64,32,1,64>(W2, hsx, &a, j);
    if (lane < 32) h2x[lane] = fmaxf(a, 0.f);
  }
  __syncthreads();
  {
    float a = B3s[lane];
    layerR<32,64,1,32>(W3, h2x, &a, lane);
    out_states[(size_t)g*64 + lane] = fmaxf(a, 0.f) + states2[(size_t)g*64 + lane];
  }
}

// ---------- launch ----------
extern "C" void kernel_launch(void* const* d_in, const int* in_sizes, int n_in,
                              void* d_out, int out_size, void* d_ws, size_t ws_size,
                              hipStream_t stream)
{
  const float* sites   = (const float*)d_in[0];
  const float* bonds   = (const float*)d_in[1];
  const float* states  = (const float*)d_in[2];
  const float* w_sites1 = (const float*)d_in[3];  const float* b_sites1 = (const float*)d_in[4];
  const float* w_sites2 = (const float*)d_in[5];  const float* b_sites2 = (const float*)d_in[6];
  const float* w_bonds1 = (const float*)d_in[7];  const float* b_bonds1 = (const float*)d_in[8];
  const float* w_bonds2 = (const float*)d_in[9];  const float* b_bonds2 = (const float*)d_in[10];
  const float* w_states1= (const float*)d_in[11]; const float* b_states1= (const float*)d_in[12];
  const float* w_states2= (const float*)d_in[13]; const float* b_states2= (const float*)d_in[14];
  const float* w_bu1 = (const float*)d_in[15]; const float* b_bu1 = (const float*)d_in[16];
  const float* w_bu2 = (const float*)d_in[17]; const float* b_bu2 = (const float*)d_in[18];
  const float* w_bu3 = (const float*)d_in[19]; const float* b_bu3 = (const float*)d_in[20];
  const float* w_su1 = (const float*)d_in[21]; const float* b_su1 = (const float*)d_in[22];
  const float* w_su2 = (const float*)d_in[23]; const float* b_su2 = (const float*)d_in[24];
  const float* w_su3 = (const float*)d_in[25]; const float* b_su3 = (const float*)d_in[26];
  const float* w_stu1= (const float*)d_in[27]; const float* b_stu1= (const float*)d_in[28];
  const float* w_stu2= (const float*)d_in[29]; const float* b_stu2= (const float*)d_in[30];
  const float* w_stu3= (const float*)d_in[31]; const float* b_stu3= (const float*)d_in[32];
  const int* idx1 = (const int*)d_in[33];
  const int* idx2 = (const int*)d_in[34];
  const int* g2s  = (const int*)d_in[35];
  const int* g2b  = (const int*)d_in[36];

  // d_ws usage: ~27.6 MB
  float* p = (float*)d_ws;
  float* bonds_pool = p;        p += (size_t)N_SITES*64;     // zeroed
  float* bonds_g    = p;        p += (size_t)N_GRAPHS*64;    // zeroed
  float* sites_g    = p;        p += (size_t)N_GRAPHS*64;    // zeroed
  int*   cnt_pool   = (int*)p;  p += N_SITES;                // zeroed
  float* states2    = p;        p += (size_t)N_GRAPHS*64;
  float* statec_bu  = p;        p += (size_t)N_GRAPHS*64;
  float* statec_su  = p;        p += (size_t)N_GRAPHS*64;
  float* statec_stu = p;        p += (size_t)N_GRAPHS*64;

  size_t zero_bytes = ((size_t)N_SITES*64 + 2*(size_t)N_GRAPHS*64 + (size_t)N_SITES) * 4;
  hipMemsetAsync(d_ws, 0, zero_bytes, stream);

  float* out_sites  = (float*)d_out;
  float* out_bonds  = out_sites + (size_t)N_SITES*64;
  float* out_states = out_bonds + (size_t)N_BONDS*64;
  float* sites2     = out_sites;   // fp32 sites2 staged in the sites output
                                   // region: written by sites_pre, gathered by
                                   // bond_kernel, read-then-overwritten in
                                   // place by site_kernel (each element only
                                   // by its owning thread).

  hipLaunchKernelGGL(prep_small_kernel, dim3(250), dim3(256), 0, stream,
      states, w_states1, b_states1, w_states2, b_states2,
      w_bu1, b_bu1, w_su1, b_su1, w_stu1, b_stu1,
      states2, statec_bu, statec_su, statec_stu);

  hipLaunchKernelGGL(sites_pre_kernel, dim3(1024), dim3(256), 0, stream,
      sites, w_sites1, b_sites1, w_sites2, b_sites2, sites2);

  // 12500 waves of 64 bonds, 16 waves/block -> 782 blocks
  hipLaunchKernelGGL(bond_kernel, dim3(782), dim3(1024), 0, stream,
      bonds, w_bonds1, b_bonds1, w_bonds2, b_bonds2,
      w_bu1, w_bu2, b_bu2, w_bu3, b_bu3,
      idx1, idx2, g2b, sites2, statec_bu,
      bonds_pool, cnt_pool, bonds_g, out_bonds);

  // 6250 waves of 16 sites, 8 waves/block -> 782 blocks
  hipLaunchKernelGGL(site_kernel, dim3(782), dim3(512), 0, stream,
      sites2, bonds_pool, cnt_pool, g2s, statec_su,
      w_su1, w_su2, b_su2, w_su3, b_su3,
      sites_g, out_sites);

  hipLaunchKernelGGL(state_kernel, dim3(1000), dim3(64), 0, stream,
      states2, bonds_g, sites_g, g2b, g2s,
      w_stu1, w_stu2, b_stu2, w_stu3, b_stu3,
      statec_stu, out_states);
}

// Round 5
// 2561.375 us; speedup vs baseline: 1.0202x; 1.0133x over previous
//
#include <hip/hip_runtime.h>

#define N_SITES  100000
#define N_BONDS  800000
#define N_GRAPHS 1000

// ---------- LDS staging helpers (fp32) ----------
template<int CNT>
__device__ __forceinline__ void stage_w(float* dst, const float* __restrict__ src, int tid, int nth){
  for (int i = tid; i < CNT; i += nth) dst[i] = src[i];
}
__device__ __forceinline__ void stage_b(float* dst, const float* __restrict__ src, int n, int tid){
  if (tid < n) dst[tid] = src[tid];
}

// acc[r] += sum_k x[r*XS + k] * W[k*N + j]
// W in LDS [K][N]: lane-consecutive reads (2-way bank alias = free).
// x in LDS, read as same-address float4 broadcasts (conflict-free).
template<int K, int N, int R, int XS>
__device__ __forceinline__ void layerR(const float* __restrict__ W,
                                       const float* __restrict__ x,
                                       float* __restrict__ acc, int j)
{
  #pragma unroll
  for (int k = 0; k < K; k += 4){
    float w0 = W[(k+0)*N + j];
    float w1 = W[(k+1)*N + j];
    float w2 = W[(k+2)*N + j];
    float w3 = W[(k+3)*N + j];
    #pragma unroll
    for (int r = 0; r < R; ++r){
      float4 xv = *(const float4*)(x + r*XS + k);
      acc[r] = fmaf(xv.x, w0, acc[r]);
      acc[r] = fmaf(xv.y, w1, acc[r]);
      acc[r] = fmaf(xv.z, w2, acc[r]);
      acc[r] = fmaf(xv.w, w3, acc[r]);
    }
  }
}

__device__ __forceinline__ int lbound(const int* __restrict__ a, int n, int v){
  int lo = 0, hi = n;
  while (lo < hi){ int m = (lo+hi) >> 1; if (a[m] < v) lo = m+1; else hi = m; }
  return lo;
}

// ---------- kernel 1: states path prep (1000 rows) ----------
__global__ __launch_bounds__(256) void prep_small_kernel(
    const float* __restrict__ states,
    const float* __restrict__ w1, const float* __restrict__ b1,
    const float* __restrict__ w2, const float* __restrict__ b2,
    const float* __restrict__ w_bu1, const float* __restrict__ b_bu1,
    const float* __restrict__ w_su1, const float* __restrict__ b_su1,
    const float* __restrict__ w_stu1, const float* __restrict__ b_stu1,
    float* __restrict__ states2, float* __restrict__ statec_bu,
    float* __restrict__ statec_su, float* __restrict__ statec_stu)
{
  __shared__ float W1[4096], W2[4096], WD[4096], WsuC[4096], WstuC[4096];
  __shared__ float B1[64], B2[64], Bbu[64], Bsu[64], Bstu[64];
  __shared__ alignas(16) float xs[4][64];
  __shared__ alignas(16) float hs[4][64];
  int tid = threadIdx.x;
  stage_w<4096>(W1,    w1,              tid, 256);
  stage_w<4096>(W2,    w2,              tid, 256);
  stage_w<4096>(WD,    w_bu1 + 192*64,  tid, 256);
  stage_w<4096>(WsuC,  w_su1 + 128*64,  tid, 256);
  stage_w<4096>(WstuC, w_stu1 + 128*64, tid, 256);
  stage_b(B1, b1, 64, tid);  stage_b(B2, b2, 64, tid);
  stage_b(Bbu, b_bu1, 64, tid); stage_b(Bsu, b_su1, 64, tid); stage_b(Bstu, b_stu1, 64, tid);
  __syncthreads();
  int w = tid >> 6, lane = tid & 63;
  int g = blockIdx.x*4 + w;                       // 250 blocks * 4 = exactly 1000
  xs[w][lane] = states[(size_t)g*64 + lane];
  float a = B1[lane];
  layerR<64,64,1,64>(W1, xs[w], &a, lane);
  hs[w][lane] = fmaxf(a, 0.f);
  a = B2[lane];
  layerR<64,64,1,64>(W2, hs[w], &a, lane);
  float s2 = fmaxf(a, 0.f);
  xs[w][lane] = s2;
  size_t o = (size_t)g*64 + lane;
  float abu = Bbu[lane], asu = Bsu[lane], astu = Bstu[lane];
  layerR<64,64,1,64>(WD,    xs[w], &abu,  lane);
  layerR<64,64,1,64>(WsuC,  xs[w], &asu,  lane);
  layerR<64,64,1,64>(WstuC, xs[w], &astu, lane);
  states2[o]    = s2;
  statec_bu[o]  = abu;
  statec_su[o]  = asu;
  statec_stu[o] = astu;
}

// ---------- kernel 2: sites pre-MLP (100000 rows) -> fp32 sites2 ----------
__global__ __launch_bounds__(256) void sites_pre_kernel(
    const float* __restrict__ sites,
    const float* __restrict__ w1, const float* __restrict__ b1,
    const float* __restrict__ w2, const float* __restrict__ b2,
    float* __restrict__ sites2)
{
  __shared__ float W1[4096], W2[4096];
  __shared__ float B1[64], B2[64];
  __shared__ alignas(16) float xs[4][4][64];
  __shared__ alignas(16) float hs[4][4][64];
  int tid = threadIdx.x;
  stage_w<4096>(W1, w1, tid, 256);
  stage_w<4096>(W2, w2, tid, 256);
  stage_b(B1, b1, 64, tid); stage_b(B2, b2, 64, tid);
  __syncthreads();
  int w = tid >> 6, lane = tid & 63;
  int wgid = blockIdx.x*4 + w;                     // 1024 blocks * 4 waves = 4096
  for (int n = 0; n < 7; ++n){                     // 7*4096 >= 25000 groups of 4 sites
    int G = n*4096 + wgid;
    if (G >= 25000) break;
    #pragma unroll
    for (int r = 0; r < 4; ++r)
      xs[w][r][lane] = sites[((size_t)(4*G + r))*64 + lane];
    {
      float a[4] = {B1[lane], B1[lane], B1[lane], B1[lane]};
      layerR<64,64,4,64>(W1, &xs[w][0][0], a, lane);
      #pragma unroll
      for (int r = 0; r < 4; ++r) hs[w][r][lane] = fmaxf(a[r], 0.f);
    }
    {
      float a[4] = {B2[lane], B2[lane], B2[lane], B2[lane]};
      layerR<64,64,4,64>(W2, &hs[w][0][0], a, lane);
      #pragma unroll
      for (int r = 0; r < 4; ++r)
        sites2[((size_t)(4*G + r))*64 + lane] = fmaxf(a[r], 0.f);
    }
  }
}

// ---------- kernel 3: bond kernel (fused bonds pre-MLP + gather + bond update) ----------
// 1024 threads = 16 waves share ONE copy of the 96 KiB of weights; LDS
// 152.9 KiB -> 1 block/CU = 4 waves/SIMD.
// REGISTER-PRESSURE design (rounds 2-4 spilled ~2.4 GB/launch at the
// allocator's 64-VGPR choice, and neither launch_bounds(.,4) nor
// amdgpu_waves_per_eu(4,4) moved it):
//  - gathers go DIRECTLY global->LDS (round 0's proven pattern), no
//    vb/v1/v2 register staging;
//  - no separate hs buffer: X is reused in place bonds_in -> h1 -> bonds2
//    (layerR fully consumes the old contents before each overwrite; DS
//    ops within a wave stay ordered because the addresses may-alias);
//  - fc1's hidden overwrites P (consumed by WA.P by then);
//  - residual b2v re-read from X at the epilogue instead of living in
//    registers across 5 layers.
// Live loop state: i1a[4], gg[4], gacc, cur_g -> fits a 64-VGPR budget.
__global__ __launch_bounds__(1024) void bond_kernel(
    const float* __restrict__ bonds,
    const float* __restrict__ wb1, const float* __restrict__ bb1,
    const float* __restrict__ wb2, const float* __restrict__ bb2,
    const float* __restrict__ w_bu1,
    const float* __restrict__ w_bu2, const float* __restrict__ b_bu2,
    const float* __restrict__ w_bu3, const float* __restrict__ b_bu3,
    const int* __restrict__ idx1, const int* __restrict__ idx2, const int* __restrict__ g2b,
    const float* __restrict__ sites2, const float* __restrict__ statec_bu,
    float* __restrict__ bonds_pool, int* __restrict__ cnt_pool, float* __restrict__ bonds_g,
    float* __restrict__ out_bonds)
{
  __shared__ float W1[4096], W2[4096], WA[4096], WB[4096], WC[4096];
  __shared__ float WU2[2048], WU3[2048];
  __shared__ float Bb1[64], Bb2[64], Bu2[32], Bu3[64];
  __shared__ alignas(16) float X[16][4][64];    // bonds_in -> h1 -> bonds2
  __shared__ alignas(16) float P[16][4][64];    // sites2[i1] -> fc1 hidden
  __shared__ alignas(16) float Q[16][4][64];    // sites2[i2]
  __shared__ alignas(16) float H2[16][4][32];
  int tid = threadIdx.x;
  stage_w<4096>(W1, wb1,            tid, 1024);
  stage_w<4096>(W2, wb2,            tid, 1024);
  stage_w<4096>(WA, w_bu1,          tid, 1024);
  stage_w<4096>(WB, w_bu1 + 64*64,  tid, 1024);
  stage_w<4096>(WC, w_bu1 + 128*64, tid, 1024);
  stage_w<2048>(WU2, w_bu2,         tid, 1024);
  stage_w<2048>(WU3, w_bu3,         tid, 1024);
  stage_b(Bb1, bb1, 64, tid); stage_b(Bb2, bb2, 64, tid);
  stage_b(Bu2, b_bu2, 32, tid); stage_b(Bu3, b_bu3, 64, tid);
  __syncthreads();
  int w = tid >> 6, lane = tid & 63;
  int ebase = blockIdx.x*1024 + w*64;   // wave owns 64 CONTIGUOUS bonds (g2b sorted)
  if (ebase >= N_BONDS) return;         // tail block: inactive waves exit after barrier
  float gacc = 0.f; int cur_g = -1;
  for (int it = 0; it < 16; ++it){
    int e0 = ebase + it*4;
    int i1a[4], gg[4];
    #pragma unroll
    for (int r = 0; r < 4; ++r){
      int e = e0 + r;
      int i1 = idx1[e], i2 = idx2[e];
      i1a[r] = i1; gg[r] = g2b[e];
      X[w][r][lane] = bonds[(size_t)e*64 + lane];
      P[w][r][lane] = sites2[(size_t)i1*64 + lane];
      Q[w][r][lane] = sites2[(size_t)i2*64 + lane];
    }
    // bonds pre-MLP layer 1 (X: bonds_in -> h1, in place)
    {
      float a[4] = {Bb1[lane], Bb1[lane], Bb1[lane], Bb1[lane]};
      layerR<64,64,4,64>(W1, &X[w][0][0], a, lane);
      #pragma unroll
      for (int r = 0; r < 4; ++r) X[w][r][lane] = fmaxf(a[r], 0.f);
    }
    // bonds pre-MLP layer 2 (X: h1 -> bonds2, in place)
    {
      float a[4] = {Bb2[lane], Bb2[lane], Bb2[lane], Bb2[lane]};
      layerR<64,64,4,64>(W2, &X[w][0][0], a, lane);
      #pragma unroll
      for (int r = 0; r < 4; ++r) X[w][r][lane] = fmaxf(a[r], 0.f);
    }
    // bond-update fc1: A*s1 + B*s2 + C*bonds2 + (state slice incl. bias)
    // hidden goes into P (P's s1 contents fully consumed by WA)
    {
      float a[4];
      #pragma unroll
      for (int r = 0; r < 4; ++r) a[r] = statec_bu[(size_t)gg[r]*64 + lane];
      layerR<64,64,4,64>(WA, &P[w][0][0], a, lane);
      layerR<64,64,4,64>(WB, &Q[w][0][0], a, lane);
      layerR<64,64,4,64>(WC, &X[w][0][0], a, lane);
      #pragma unroll
      for (int r = 0; r < 4; ++r) P[w][r][lane] = fmaxf(a[r], 0.f);
    }
    // bond-update fc2 (64 -> 32); all lanes compute j=lane&31, low lanes write
    {
      int j = lane & 31;
      float a[4] = {Bu2[j], Bu2[j], Bu2[j], Bu2[j]};
      layerR<64,32,4,64>(WU2, &P[w][0][0], a, j);
      if (lane < 32){
        #pragma unroll
        for (int r = 0; r < 4; ++r) H2[w][r][lane] = fmaxf(a[r], 0.f);
      }
    }
    // bond-update fc3 (32 -> 64) + epilogue (b2v re-read from X)
    {
      float a[4] = {Bu3[lane], Bu3[lane], Bu3[lane], Bu3[lane]};
      layerR<32,64,4,32>(WU3, &H2[w][0][0], a, lane);
      #pragma unroll
      for (int r = 0; r < 4; ++r){
        float bnew = fmaxf(a[r], 0.f);
        int e = e0 + r;
        out_bonds[(size_t)e*64 + lane] = bnew + X[w][r][lane];
        atomicAdd(&bonds_pool[(size_t)i1a[r]*64 + lane], bnew);
        if (lane == 0) atomicAdd(&cnt_pool[i1a[r]], 1);
        if (gg[r] != cur_g){
          if (cur_g >= 0) atomicAdd(&bonds_g[(size_t)cur_g*64 + lane], gacc);
          cur_g = gg[r]; gacc = 0.f;
        }
        gacc += bnew;
      }
    }
  }
  if (cur_g >= 0) atomicAdd(&bonds_g[(size_t)cur_g*64 + lane], gacc);
}

// ---------- kernel 4: site update (100000 rows) ----------
// Same low-pressure treatment: direct global->LDS, P reused in place for
// the fc1 hidden, residual s2v re-read from Q. LDS 68.4 KiB -> 2 blocks/CU.
__global__ __launch_bounds__(512) void site_kernel(
    const float* __restrict__ sites2, const float* __restrict__ bonds_pool, const int* __restrict__ cnt_pool,
    const int* __restrict__ g2s, const float* __restrict__ statec_su,
    const float* __restrict__ w_su1, const float* __restrict__ w_su2, const float* __restrict__ b_su2,
    const float* __restrict__ w_su3, const float* __restrict__ b_su3,
    float* __restrict__ sites_g, float* __restrict__ out_sites)
{
  __shared__ float W1a[4096], W1b[4096], W2[2048], W3[2048];
  __shared__ float B2s[32], B3s[64];
  __shared__ alignas(16) float P[8][4][64];    // pooled bonds -> fc1 hidden
  __shared__ alignas(16) float Q[8][4][64];    // sites2 (kept for residual)
  __shared__ alignas(16) float H2[8][4][32];
  int tid = threadIdx.x;
  stage_w<4096>(W1a, w_su1,         tid, 512);
  stage_w<4096>(W1b, w_su1 + 64*64, tid, 512);
  stage_w<2048>(W2,  w_su2,         tid, 512);
  stage_w<2048>(W3,  w_su3,         tid, 512);
  stage_b(B2s, b_su2, 32, tid); stage_b(B3s, b_su3, 64, tid);
  __syncthreads();
  int w = tid >> 6, lane = tid & 63;
  int sbase = (blockIdx.x*8 + w)*16;    // contiguous sites per wave (g2s sorted)
  if (sbase >= N_SITES) return;
  float gacc = 0.f; int cur_g = -1;
  for (int it = 0; it < 4; ++it){
    int s0 = sbase + it*4;
    int gg[4];
    #pragma unroll
    for (int r = 0; r < 4; ++r){
      int s = s0 + r;
      gg[r] = g2s[s];
      float inv = 1.f / fmaxf((float)cnt_pool[s], 1.f);
      P[w][r][lane] = bonds_pool[(size_t)s*64 + lane] * inv;
      Q[w][r][lane] = sites2[(size_t)s*64 + lane];
    }
    {
      float a[4];
      #pragma unroll
      for (int r = 0; r < 4; ++r) a[r] = statec_su[(size_t)gg[r]*64 + lane];
      layerR<64,64,4,64>(W1a, &P[w][0][0], a, lane);
      layerR<64,64,4,64>(W1b, &Q[w][0][0], a, lane);
      #pragma unroll
      for (int r = 0; r < 4; ++r) P[w][r][lane] = fmaxf(a[r], 0.f);
    }
    {
      int j = lane & 31;
      float a[4] = {B2s[j], B2s[j], B2s[j], B2s[j]};
      layerR<64,32,4,64>(W2, &P[w][0][0], a, j);
      if (lane < 32){
        #pragma unroll
        for (int r = 0; r < 4; ++r) H2[w][r][lane] = fmaxf(a[r], 0.f);
      }
    }
    {
      float a[4] = {B3s[lane], B3s[lane], B3s[lane], B3s[lane]};
      layerR<32,64,4,32>(W3, &H2[w][0][0], a, lane);
      #pragma unroll
      for (int r = 0; r < 4; ++r){
        int s = s0 + r;
        float snew = fmaxf(a[r], 0.f);
        out_sites[(size_t)s*64 + lane] = snew + Q[w][r][lane];
        if (gg[r] != cur_g){
          if (cur_g >= 0) atomicAdd(&sites_g[(size_t)cur_g*64 + lane], gacc);
          cur_g = gg[r]; gacc = 0.f;
        }
        gacc += snew;
      }
    }
  }
  if (cur_g >= 0) atomicAdd(&sites_g[(size_t)cur_g*64 + lane], gacc);
}

// ---------- kernel 5: state update (1000 graphs, one wave each) ----------
// Barriers REQUIRED around cooperative staging (round-1 failure: per-lane
// alias analysis can't see lane->lane staging deps).
__global__ __launch_bounds__(64) void state_kernel(
    const float* __restrict__ states2, const float* __restrict__ bonds_g, const float* __restrict__ sites_g,
    const int* __restrict__ g2b, const int* __restrict__ g2s,
    const float* __restrict__ w_stu1, const float* __restrict__ w_stu2, const float* __restrict__ b_stu2,
    const float* __restrict__ w_stu3, const float* __restrict__ b_stu3,
    const float* __restrict__ statec_stu, float* __restrict__ out_states)
{
  __shared__ float W1a[4096], W1b[4096], W2[2048], W3[2048];
  __shared__ float B2s[32], B3s[64];
  __shared__ alignas(16) float xb[64], xsit[64], hsx[64], h2x[32];
  __shared__ int cnts[2];
  int lane = threadIdx.x; int g = blockIdx.x;
  stage_w<4096>(W1a, w_stu1,         lane, 64);
  stage_w<4096>(W1b, w_stu1 + 64*64, lane, 64);
  stage_w<2048>(W2,  w_stu2,         lane, 64);
  stage_w<2048>(W3,  w_stu3,         lane, 64);
  stage_b(B2s, b_stu2, 32, lane); stage_b(B3s, b_stu3, 64, lane);
  if (lane == 0){
    cnts[0] = lbound(g2b, N_BONDS, g+1) - lbound(g2b, N_BONDS, g);
    cnts[1] = lbound(g2s, N_SITES, g+1) - lbound(g2s, N_SITES, g);
  }
  __syncthreads();
  float invb = 1.f / fmaxf((float)cnts[0], 1.f);
  float invs = 1.f / fmaxf((float)cnts[1], 1.f);
  xb[lane]   = bonds_g[(size_t)g*64 + lane] * invb;
  xsit[lane] = sites_g[(size_t)g*64 + lane] * invs;
  __syncthreads();
  {
    float a = statec_stu[(size_t)g*64 + lane];
    layerR<64,64,1,64>(W1a, xb,   &a, lane);
    layerR<64,64,1,64>(W1b, xsit, &a, lane);
    hsx[lane] = fmaxf(a, 0.f);
  }
  __syncthreads();
  {
    int j = lane & 31;
    float a = B2s[j];
    layerR<64,32,1,64>(W2, hsx, &a, j);
    if (lane < 32) h2x[lane] = fmaxf(a, 0.f);
  }
  __syncthreads();
  {
    float a = B3s[lane];
    layerR<32,64,1,32>(W3, h2x, &a, lane);
    out_states[(size_t)g*64 + lane] = fmaxf(a, 0.f) + states2[(size_t)g*64 + lane];
  }
}

// ---------- launch ----------
extern "C" void kernel_launch(void* const* d_in, const int* in_sizes, int n_in,
                              void* d_out, int out_size, void* d_ws, size_t ws_size,
                              hipStream_t stream)
{
  const float* sites   = (const float*)d_in[0];
  const float* bonds   = (const float*)d_in[1];
  const float* states  = (const float*)d_in[2];
  const float* w_sites1 = (const float*)d_in[3];  const float* b_sites1 = (const float*)d_in[4];
  const float* w_sites2 = (const float*)d_in[5];  const float* b_sites2 = (const float*)d_in[6];
  const float* w_bonds1 = (const float*)d_in[7];  const float* b_bonds1 = (const float*)d_in[8];
  const float* w_bonds2 = (const float*)d_in[9];  const float* b_bonds2 = (const float*)d_in[10];
  const float* w_states1= (const float*)d_in[11]; const float* b_states1= (const float*)d_in[12];
  const float* w_states2= (const float*)d_in[13]; const float* b_states2= (const float*)d_in[14];
  const float* w_bu1 = (const float*)d_in[15]; const float* b_bu1 = (const float*)d_in[16];
  const float* w_bu2 = (const float*)d_in[17]; const float* b_bu2 = (const float*)d_in[18];
  const float* w_bu3 = (const float*)d_in[19]; const float* b_bu3 = (const float*)d_in[20];
  const float* w_su1 = (const float*)d_in[21]; const float* b_su1 = (const float*)d_in[22];
  const float* w_su2 = (const float*)d_in[23]; const float* b_su2 = (const float*)d_in[24];
  const float* w_su3 = (const float*)d_in[25]; const float* b_su3 = (const float*)d_in[26];
  const float* w_stu1= (const float*)d_in[27]; const float* b_stu1= (const float*)d_in[28];
  const float* w_stu2= (const float*)d_in[29]; const float* b_stu2= (const float*)d_in[30];
  const float* w_stu3= (const float*)d_in[31]; const float* b_stu3= (const float*)d_in[32];
  const int* idx1 = (const int*)d_in[33];
  const int* idx2 = (const int*)d_in[34];
  const int* g2s  = (const int*)d_in[35];
  const int* g2b  = (const int*)d_in[36];

  // d_ws usage: ~27.6 MB
  float* p = (float*)d_ws;
  float* bonds_pool = p;        p += (size_t)N_SITES*64;     // zeroed
  float* bonds_g    = p;        p += (size_t)N_GRAPHS*64;    // zeroed
  float* sites_g    = p;        p += (size_t)N_GRAPHS*64;    // zeroed
  int*   cnt_pool   = (int*)p;  p += N_SITES;                // zeroed
  float* states2    = p;        p += (size_t)N_GRAPHS*64;
  float* statec_bu  = p;        p += (size_t)N_GRAPHS*64;
  float* statec_su  = p;        p += (size_t)N_GRAPHS*64;
  float* statec_stu = p;        p += (size_t)N_GRAPHS*64;

  size_t zero_bytes = ((size_t)N_SITES*64 + 2*(size_t)N_GRAPHS*64 + (size_t)N_SITES) * 4;
  hipMemsetAsync(d_ws, 0, zero_bytes, stream);

  float* out_sites  = (float*)d_out;
  float* out_bonds  = out_sites + (size_t)N_SITES*64;
  float* out_states = out_bonds + (size_t)N_BONDS*64;
  float* sites2     = out_sites;   // fp32 sites2 staged in the sites output
                                   // region: written by sites_pre, gathered by
                                   // bond_kernel, read-then-overwritten in
                                   // place by site_kernel (each element only
                                   // by its owning thread).

  hipLaunchKernelGGL(prep_small_kernel, dim3(250), dim3(256), 0, stream,
      states, w_states1, b_states1, w_states2, b_states2,
      w_bu1, b_bu1, w_su1, b_su1, w_stu1, b_stu1,
      states2, statec_bu, statec_su, statec_stu);

  hipLaunchKernelGGL(sites_pre_kernel, dim3(1024), dim3(256), 0, stream,
      sites, w_sites1, b_sites1, w_sites2, b_sites2, sites2);

  // 12500 waves of 64 bonds, 16 waves/block -> 782 blocks
  hipLaunchKernelGGL(bond_kernel, dim3(782), dim3(1024), 0, stream,
      bonds, w_bonds1, b_bonds1, w_bonds2, b_bonds2,
      w_bu1, w_bu2, b_bu2, w_bu3, b_bu3,
      idx1, idx2, g2b, sites2, statec_bu,
      bonds_pool, cnt_pool, bonds_g, out_bonds);

  // 6250 waves of 16 sites, 8 waves/block -> 782 blocks
  hipLaunchKernelGGL(site_kernel, dim3(782), dim3(512), 0, stream,
      sites2, bonds_pool, cnt_pool, g2s, statec_su,
      w_su1, w_su2, b_su2, w_su3, b_su3,
      sites_g, out_sites);

  hipLaunchKernelGGL(state_kernel, dim3(1000), dim3(64), 0, stream,
      states2, bonds_g, sites_g, g2b, g2s,
      w_stu1, w_stu2, b_stu2, w_stu3, b_stu3,
      statec_stu, out_states);
}

// Round 6
// 1084.828 us; speedup vs baseline: 2.4089x; 2.3611x over previous
//
#include <hip/hip_runtime.h>

#define N_SITES  100000
#define N_BONDS  800000
#define N_GRAPHS 1000

// ---------- MFMA types (per guide: short8 = 8 bf16 = 4 VGPRs) ----------
typedef short bfx8 __attribute__((ext_vector_type(8)));
typedef float fx4  __attribute__((ext_vector_type(4)));

// ---------- swizzled bf16 LDS helpers ----------
// 128B-row-stride buffers ([64 rows][64 elems]); XOR swizzle ^((row&7)<<4)
// stays within the row (bits 4-6 < 128) and spreads 16-lane row-walks
// across 8 distinct 16B slots -> <=2-way bank conflict (free, m136).
__device__ __forceinline__ bfx8 ldfrag128(const short* buf, int row, int k){
  int off = (row*128 + k*2) ^ ((row&7)<<4);
  return *(const bfx8*)((const char*)buf + off);
}
// 64B-row-stride buffers ([64 rows][32 elems]); same XOR is bijective
// (bit6 ^= row.bit2 is invertible since row bits stay in addr bits >=6).
__device__ __forceinline__ bfx8 ldfrag64(const short* buf, int row, int k){
  int off = (row*64 + k*2) ^ ((row&7)<<4);
  return *(const bfx8*)((const char*)buf + off);
}
__device__ __forceinline__ void stb16_128(short* buf, int row, int col, float v){
  int off = (row*128 + col*2) ^ ((row&7)<<4);
  *(__bf16*)((char*)buf + off) = (__bf16)v;
}
__device__ __forceinline__ float ldb16_128(const short* buf, int row, int col){
  int off = (row*128 + col*2) ^ ((row&7)<<4);
  return (float)*(const __bf16*)((const char*)buf + off);
}
__device__ __forceinline__ void stb16_64(short* buf, int row, int col, float v){
  int off = (row*64 + col*2) ^ ((row&7)<<4);
  *(__bf16*)((char*)buf + off) = (__bf16)v;
}

// D(64x64) += A(64x64) @ B(64x64), A/B bf16 in swizzled LDS, acc f32.
// A-frag: lane l holds A[mt*16 + l%16][kt*32 + (l/16)*8 + 0..7]
// B-frag: lane l holds B[kt*32 + (l/16)*8 + 0..7][nt*16 + l%16]  (stored [n][k])
// C/D:    lane l holds D[mt*16 + (l/16)*4 + i][nt*16 + l%16]     (verified m89)
__device__ __forceinline__ void gemm64(const short* Ab, const short* Bw,
                                       fx4 (&acc)[4][4], int q, int c){
  #pragma unroll
  for (int kt = 0; kt < 2; ++kt){
    int k = kt*32 + q*8;
    bfx8 a0 = ldfrag128(Ab,  0+c, k);
    bfx8 a1 = ldfrag128(Ab, 16+c, k);
    bfx8 a2 = ldfrag128(Ab, 32+c, k);
    bfx8 a3 = ldfrag128(Ab, 48+c, k);
    #pragma unroll
    for (int nt = 0; nt < 4; ++nt){
      bfx8 b = ldfrag128(Bw, nt*16+c, k);
      acc[0][nt] = __builtin_amdgcn_mfma_f32_16x16x32_bf16(a0, b, acc[0][nt], 0,0,0);
      acc[1][nt] = __builtin_amdgcn_mfma_f32_16x16x32_bf16(a1, b, acc[1][nt], 0,0,0);
      acc[2][nt] = __builtin_amdgcn_mfma_f32_16x16x32_bf16(a2, b, acc[2][nt], 0,0,0);
      acc[3][nt] = __builtin_amdgcn_mfma_f32_16x16x32_bf16(a3, b, acc[3][nt], 0,0,0);
    }
  }
}
__device__ __forceinline__ void initbias(fx4 (&acc)[4][4], const float* B, int c){
  #pragma unroll
  for (int nt = 0; nt < 4; ++nt){
    float bv = B[nt*16+c];
    fx4 v = {bv, bv, bv, bv};
    #pragma unroll
    for (int mt = 0; mt < 4; ++mt) acc[mt][nt] = v;
  }
}
__device__ __forceinline__ void wbC128(short* dst, fx4 (&acc)[4][4], int q, int c){
  #pragma unroll
  for (int mt = 0; mt < 4; ++mt)
    #pragma unroll
    for (int nt = 0; nt < 4; ++nt)
      #pragma unroll
      for (int i = 0; i < 4; ++i)
        stb16_128(dst, mt*16+q*4+i, nt*16+c, fmaxf(acc[mt][nt][i], 0.f));
}

// ---------- scalar LDS staging helpers (fp32, unchanged kernels) ----------
template<int CNT>
__device__ __forceinline__ void stage_w(float* dst, const float* __restrict__ src, int tid, int nth){
  for (int i = tid; i < CNT; i += nth) dst[i] = src[i];
}
__device__ __forceinline__ void stage_b(float* dst, const float* __restrict__ src, int n, int tid){
  if (tid < n) dst[tid] = src[tid];
}

template<int K, int N, int R, int XS>
__device__ __forceinline__ void layerR(const float* __restrict__ W,
                                       const float* __restrict__ x,
                                       float* __restrict__ acc, int j)
{
  #pragma unroll
  for (int k = 0; k < K; k += 4){
    float w0 = W[(k+0)*N + j];
    float w1 = W[(k+1)*N + j];
    float w2 = W[(k+2)*N + j];
    float w3 = W[(k+3)*N + j];
    #pragma unroll
    for (int r = 0; r < R; ++r){
      float4 xv = *(const float4*)(x + r*XS + k);
      acc[r] = fmaf(xv.x, w0, acc[r]);
      acc[r] = fmaf(xv.y, w1, acc[r]);
      acc[r] = fmaf(xv.z, w2, acc[r]);
      acc[r] = fmaf(xv.w, w3, acc[r]);
    }
  }
}

__device__ __forceinline__ int lbound(const int* __restrict__ a, int n, int v){
  int lo = 0, hi = n;
  while (lo < hi){ int m = (lo+hi) >> 1; if (a[m] < v) lo = m+1; else hi = m; }
  return lo;
}

// ---------- kernel 1: states path prep (1000 rows) ----------
__global__ __launch_bounds__(256) void prep_small_kernel(
    const float* __restrict__ states,
    const float* __restrict__ w1, const float* __restrict__ b1,
    const float* __restrict__ w2, const float* __restrict__ b2,
    const float* __restrict__ w_bu1, const float* __restrict__ b_bu1,
    const float* __restrict__ w_su1, const float* __restrict__ b_su1,
    const float* __restrict__ w_stu1, const float* __restrict__ b_stu1,
    float* __restrict__ states2, float* __restrict__ statec_bu,
    float* __restrict__ statec_su, float* __restrict__ statec_stu)
{
  __shared__ float W1[4096], W2[4096], WD[4096], WsuC[4096], WstuC[4096];
  __shared__ float B1[64], B2[64], Bbu[64], Bsu[64], Bstu[64];
  __shared__ alignas(16) float xs[4][64];
  __shared__ alignas(16) float hs[4][64];
  int tid = threadIdx.x;
  stage_w<4096>(W1,    w1,              tid, 256);
  stage_w<4096>(W2,    w2,              tid, 256);
  stage_w<4096>(WD,    w_bu1 + 192*64,  tid, 256);
  stage_w<4096>(WsuC,  w_su1 + 128*64,  tid, 256);
  stage_w<4096>(WstuC, w_stu1 + 128*64, tid, 256);
  stage_b(B1, b1, 64, tid);  stage_b(B2, b2, 64, tid);
  stage_b(Bbu, b_bu1, 64, tid); stage_b(Bsu, b_su1, 64, tid); stage_b(Bstu, b_stu1, 64, tid);
  __syncthreads();
  int w = tid >> 6, lane = tid & 63;
  int g = blockIdx.x*4 + w;
  xs[w][lane] = states[(size_t)g*64 + lane];
  float a = B1[lane];
  layerR<64,64,1,64>(W1, xs[w], &a, lane);
  hs[w][lane] = fmaxf(a, 0.f);
  a = B2[lane];
  layerR<64,64,1,64>(W2, hs[w], &a, lane);
  float s2 = fmaxf(a, 0.f);
  xs[w][lane] = s2;
  size_t o = (size_t)g*64 + lane;
  float abu = Bbu[lane], asu = Bsu[lane], astu = Bstu[lane];
  layerR<64,64,1,64>(WD,    xs[w], &abu,  lane);
  layerR<64,64,1,64>(WsuC,  xs[w], &asu,  lane);
  layerR<64,64,1,64>(WstuC, xs[w], &astu, lane);
  states2[o]    = s2;
  statec_bu[o]  = abu;
  statec_su[o]  = asu;
  statec_stu[o] = astu;
}

// ---------- kernel 2: sites pre-MLP (100000 rows) -> fp32 sites2 ----------
__global__ __launch_bounds__(256) void sites_pre_kernel(
    const float* __restrict__ sites,
    const float* __restrict__ w1, const float* __restrict__ b1,
    const float* __restrict__ w2, const float* __restrict__ b2,
    float* __restrict__ sites2)
{
  __shared__ float W1[4096], W2[4096];
  __shared__ float B1[64], B2[64];
  __shared__ alignas(16) float xs[4][4][64];
  __shared__ alignas(16) float hs[4][4][64];
  int tid = threadIdx.x;
  stage_w<4096>(W1, w1, tid, 256);
  stage_w<4096>(W2, w2, tid, 256);
  stage_b(B1, b1, 64, tid); stage_b(B2, b2, 64, tid);
  __syncthreads();
  int w = tid >> 6, lane = tid & 63;
  int wgid = blockIdx.x*4 + w;
  for (int n = 0; n < 7; ++n){
    int G = n*4096 + wgid;
    if (G >= 25000) break;
    #pragma unroll
    for (int r = 0; r < 4; ++r)
      xs[w][r][lane] = sites[((size_t)(4*G + r))*64 + lane];
    {
      float a[4] = {B1[lane], B1[lane], B1[lane], B1[lane]};
      layerR<64,64,4,64>(W1, &xs[w][0][0], a, lane);
      #pragma unroll
      for (int r = 0; r < 4; ++r) hs[w][r][lane] = fmaxf(a[r], 0.f);
    }
    {
      float a[4] = {B2[lane], B2[lane], B2[lane], B2[lane]};
      layerR<64,64,4,64>(W2, &hs[w][0][0], a, lane);
      #pragma unroll
      for (int r = 0; r < 4; ++r)
        sites2[((size_t)(4*G + r))*64 + lane] = fmaxf(a[r], 0.f);
    }
  }
}

// ---------- kernel 3: MFMA bond kernel ----------
// Rounds 0-5 proved the scalar bond path is LDS-ISSUE-bound (~13.3k LDS
// instrs / 64 bonds saturates the per-CU LDS pipe at ~2.07ms regardless of
// occupancy). MFMA replaces it with 192 mfma_16x16x32_bf16 + ~700 LDS ops
// per 64 bonds (~18x less LDS issue). bf16 inputs, f32 accum; harness
// threshold is bf16-scaled (9.2e-2).
// Per wave: one 64-bond block. X: bonds_in -> B2 (residual); G: H -> S1 ->
// S2 -> H1 -> H2 (in-place, same-wave DS ordering — validated pattern).
// 4 waves/block, LDS ~115 KB -> 1 block/CU.
__global__ __launch_bounds__(256) void bond_kernel(
    const float* __restrict__ bonds,
    const float* __restrict__ wb1, const float* __restrict__ bb1,
    const float* __restrict__ wb2, const float* __restrict__ bb2,
    const float* __restrict__ w_bu1,
    const float* __restrict__ w_bu2, const float* __restrict__ b_bu2,
    const float* __restrict__ w_bu3, const float* __restrict__ b_bu3,
    const int* __restrict__ idx1, const int* __restrict__ idx2, const int* __restrict__ g2b,
    const float* __restrict__ sites2, const float* __restrict__ statec_bu,
    float* __restrict__ bonds_pool, int* __restrict__ cnt_pool, float* __restrict__ bonds_g,
    float* __restrict__ out_bonds)
{
  // weights transposed [n][k] bf16, swizzled
  __shared__ alignas(16) short WT1[4096], WT2[4096], WTA[4096], WTB[4096], WTC[4096];
  __shared__ alignas(16) short WTU2[2048];   // [32 n][64 k], stride 128B
  __shared__ alignas(16) short WTU3[2048];   // [64 n][32 k], stride 64B
  __shared__ float BB1[64], BB2[64], BU2[32], BU3[64];
  __shared__ alignas(16) short Xb[4][4096];  // per-wave [64][64] bf16 swizzled
  __shared__ alignas(16) short Gb[4][4096];
  __shared__ int I1w[4][64], GGw[4][64];
  int tid = threadIdx.x;
  // ---- stage weights: transpose + bf16 + swizzle (coalesced global reads)
  {
    const float* srcs3[5] = {wb1, wb2, w_bu1, w_bu1 + 64*64, w_bu1 + 128*64};
    short* dsts3[5] = {WT1, WT2, WTA, WTB, WTC};
    #pragma unroll
    for (int m = 0; m < 5; ++m){
      const float* s = srcs3[m]; short* d = dsts3[m];
      for (int i = tid; i < 4096; i += 256){
        int k = i >> 6, n = i & 63;
        int off = (n*128 + k*2) ^ ((n&7)<<4);
        *(__bf16*)((char*)d + off) = (__bf16)s[i];
      }
    }
    for (int i = tid; i < 2048; i += 256){        // w_bu2 [64][32]
      int k = i >> 5, n = i & 31;
      int off = (n*128 + k*2) ^ ((n&7)<<4);
      *(__bf16*)((char*)WTU2 + off) = (__bf16)w_bu2[i];
    }
    for (int i = tid; i < 2048; i += 256){        // w_bu3 [32][64]
      int k = i >> 6, n = i & 63;
      int off = (n*64 + k*2) ^ ((n&7)<<4);
      *(__bf16*)((char*)WTU3 + off) = (__bf16)w_bu3[i];
    }
    stage_b(BB1, bb1, 64, tid); stage_b(BB2, bb2, 64, tid);
    stage_b(BU2, b_bu2, 32, tid); stage_b(BU3, b_bu3, 64, tid);
  }
  __syncthreads();

  int w = tid >> 6, lane = tid & 63, q = lane >> 4, c = lane & 15;
  int e0 = (blockIdx.x*4 + w) * 64;     // 3125*4*64 = exactly 800000
  short* X = Xb[w];
  short* G = Gb[w];

  // ---- stage indices + per-bond count
  {
    int i1l = idx1[e0 + lane];
    I1w[w][lane] = i1l;
    GGw[w][lane] = g2b[e0 + lane];
    atomicAdd(&cnt_pool[i1l], 1);
  }
  // ---- stage bonds -> X (bf16, swizzled)
  #pragma unroll 8
  for (int r = 0; r < 64; ++r){
    float v = bonds[(size_t)(e0 + r)*64 + lane];
    stb16_128(X, r, lane, v);
  }

  fx4 acc[4][4];
  // L1: H = relu(X @ W1 + b1) -> G
  initbias(acc, BB1, c);
  gemm64(X, WT1, acc, q, c);
  wbC128(G, acc, q, c);
  // L2: B2 = relu(G @ W2 + b2) -> X (residual lives here)
  initbias(acc, BB2, c);
  gemm64(G, WT2, acc, q, c);
  wbC128(X, acc, q, c);

  // stage S1 = sites2[idx1] -> G (H fully consumed)
  #pragma unroll 8
  for (int r = 0; r < 64; ++r){
    int i1 = I1w[w][r];
    stb16_128(G, r, lane, sites2[(size_t)i1*64 + lane]);
  }
  // fc1: acc = statec_bu rows (incl. b_bu1) + S1@WA + S2@WB + B2@WC
  #pragma unroll
  for (int mt = 0; mt < 4; ++mt)
    #pragma unroll
    for (int i = 0; i < 4; ++i){
      int g = GGw[w][mt*16 + q*4 + i];
      #pragma unroll
      for (int nt = 0; nt < 4; ++nt)
        acc[mt][nt][i] = statec_bu[(size_t)g*64 + nt*16 + c];
    }
  gemm64(G, WTA, acc, q, c);
  // stage S2 = sites2[idx2] -> G (S1 consumed)
  #pragma unroll 8
  for (int r = 0; r < 64; ++r){
    int i2 = idx2[e0 + r];
    stb16_128(G, r, lane, sites2[(size_t)i2*64 + lane]);
  }
  gemm64(G, WTB, acc, q, c);
  gemm64(X, WTC, acc, q, c);
  wbC128(G, acc, q, c);                 // H1 -> G

  // fc2: H2(64x32) = relu(H1 @ WU2 + b2) -> G (stride-64 layout, H1 consumed)
  {
    fx4 a2[4][2];
    #pragma unroll
    for (int nt = 0; nt < 2; ++nt){
      float bv = BU2[nt*16 + c];
      fx4 v = {bv, bv, bv, bv};
      #pragma unroll
      for (int mt = 0; mt < 4; ++mt) a2[mt][nt] = v;
    }
    #pragma unroll
    for (int kt = 0; kt < 2; ++kt){
      int k = kt*32 + q*8;
      bfx8 f0 = ldfrag128(G,  0+c, k);
      bfx8 f1 = ldfrag128(G, 16+c, k);
      bfx8 f2 = ldfrag128(G, 32+c, k);
      bfx8 f3 = ldfrag128(G, 48+c, k);
      #pragma unroll
      for (int nt = 0; nt < 2; ++nt){
        bfx8 b = ldfrag128(WTU2, nt*16+c, k);
        a2[0][nt] = __builtin_amdgcn_mfma_f32_16x16x32_bf16(f0, b, a2[0][nt], 0,0,0);
        a2[1][nt] = __builtin_amdgcn_mfma_f32_16x16x32_bf16(f1, b, a2[1][nt], 0,0,0);
        a2[2][nt] = __builtin_amdgcn_mfma_f32_16x16x32_bf16(f2, b, a2[2][nt], 0,0,0);
        a2[3][nt] = __builtin_amdgcn_mfma_f32_16x16x32_bf16(f3, b, a2[3][nt], 0,0,0);
      }
    }
    #pragma unroll
    for (int mt = 0; mt < 4; ++mt)
      #pragma unroll
      for (int nt = 0; nt < 2; ++nt)
        #pragma unroll
        for (int i = 0; i < 4; ++i)
          stb16_64(G, mt*16+q*4+i, nt*16+c, fmaxf(a2[mt][nt][i], 0.f));
  }
  // fc3: out(64x64) = relu(H2 @ WU3 + b3)
  {
    initbias(acc, BU3, c);
    int k = q*8;                        // K=32, single kt
    bfx8 f0 = ldfrag64(G,  0+c, k);
    bfx8 f1 = ldfrag64(G, 16+c, k);
    bfx8 f2 = ldfrag64(G, 32+c, k);
    bfx8 f3 = ldfrag64(G, 48+c, k);
    #pragma unroll
    for (int nt = 0; nt < 4; ++nt){
      bfx8 b = ldfrag64(WTU3, nt*16+c, k);
      acc[0][nt] = __builtin_amdgcn_mfma_f32_16x16x32_bf16(f0, b, acc[0][nt], 0,0,0);
      acc[1][nt] = __builtin_amdgcn_mfma_f32_16x16x32_bf16(f1, b, acc[1][nt], 0,0,0);
      acc[2][nt] = __builtin_amdgcn_mfma_f32_16x16x32_bf16(f2, b, acc[2][nt], 0,0,0);
      acc[3][nt] = __builtin_amdgcn_mfma_f32_16x16x32_bf16(f3, b, acc[3][nt], 0,0,0);
    }
  }
  // ---- epilogue: residual + stores + pool atomics + per-graph accumulation
  #pragma unroll
  for (int nt = 0; nt < 4; ++nt){
    int col = nt*16 + c;
    float ga = 0.f; int cg = -1;
    #pragma unroll
    for (int mt = 0; mt < 4; ++mt){
      #pragma unroll
      for (int i = 0; i < 4; ++i){
        int row = mt*16 + q*4 + i;
        float bn = fmaxf(acc[mt][nt][i], 0.f);
        float b2 = ldb16_128(X, row, col);
        out_bonds[(size_t)(e0 + row)*64 + col] = bn + b2;
        atomicAdd(&bonds_pool[(size_t)I1w[w][row]*64 + col], bn);
        int g = GGw[w][row];
        if (g != cg){
          if (cg >= 0) atomicAdd(&bonds_g[(size_t)cg*64 + col], ga);
          cg = g; ga = 0.f;
        }
        ga += bn;
      }
    }
    if (cg >= 0) atomicAdd(&bonds_g[(size_t)cg*64 + col], ga);
  }
}

// ---------- kernel 4: site update (100000 rows) ----------
__global__ __launch_bounds__(512) void site_kernel(
    const float* __restrict__ sites2, const float* __restrict__ bonds_pool, const int* __restrict__ cnt_pool,
    const int* __restrict__ g2s, const float* __restrict__ statec_su,
    const float* __restrict__ w_su1, const float* __restrict__ w_su2, const float* __restrict__ b_su2,
    const float* __restrict__ w_su3, const float* __restrict__ b_su3,
    float* __restrict__ sites_g, float* __restrict__ out_sites)
{
  __shared__ float W1a[4096], W1b[4096], W2[2048], W3[2048];
  __shared__ float B2s[32], B3s[64];
  __shared__ alignas(16) float P[8][4][64];
  __shared__ alignas(16) float Q[8][4][64];
  __shared__ alignas(16) float H2[8][4][32];
  int tid = threadIdx.x;
  stage_w<4096>(W1a, w_su1,         tid, 512);
  stage_w<4096>(W1b, w_su1 + 64*64, tid, 512);
  stage_w<2048>(W2,  w_su2,         tid, 512);
  stage_w<2048>(W3,  w_su3,         tid, 512);
  stage_b(B2s, b_su2, 32, tid); stage_b(B3s, b_su3, 64, tid);
  __syncthreads();
  int w = tid >> 6, lane = tid & 63;
  int sbase = (blockIdx.x*8 + w)*16;
  if (sbase >= N_SITES) return;
  float gacc = 0.f; int cur_g = -1;
  for (int it = 0; it < 4; ++it){
    int s0 = sbase + it*4;
    int gg[4];
    #pragma unroll
    for (int r = 0; r < 4; ++r){
      int s = s0 + r;
      gg[r] = g2s[s];
      float inv = 1.f / fmaxf((float)cnt_pool[s], 1.f);
      P[w][r][lane] = bonds_pool[(size_t)s*64 + lane] * inv;
      Q[w][r][lane] = sites2[(size_t)s*64 + lane];
    }
    {
      float a[4];
      #pragma unroll
      for (int r = 0; r < 4; ++r) a[r] = statec_su[(size_t)gg[r]*64 + lane];
      layerR<64,64,4,64>(W1a, &P[w][0][0], a, lane);
      layerR<64,64,4,64>(W1b, &Q[w][0][0], a, lane);
      #pragma unroll
      for (int r = 0; r < 4; ++r) P[w][r][lane] = fmaxf(a[r], 0.f);
    }
    {
      int j = lane & 31;
      float a[4] = {B2s[j], B2s[j], B2s[j], B2s[j]};
      layerR<64,32,4,64>(W2, &P[w][0][0], a, j);
      if (lane < 32){
        #pragma unroll
        for (int r = 0; r < 4; ++r) H2[w][r][lane] = fmaxf(a[r], 0.f);
      }
    }
    {
      float a[4] = {B3s[lane], B3s[lane], B3s[lane], B3s[lane]};
      layerR<32,64,4,32>(W3, &H2[w][0][0], a, lane);
      #pragma unroll
      for (int r = 0; r < 4; ++r){
        int s = s0 + r;
        float snew = fmaxf(a[r], 0.f);
        out_sites[(size_t)s*64 + lane] = snew + Q[w][r][lane];
        if (gg[r] != cur_g){
          if (cur_g >= 0) atomicAdd(&sites_g[(size_t)cur_g*64 + lane], gacc);
          cur_g = gg[r]; gacc = 0.f;
        }
        gacc += snew;
      }
    }
  }
  if (cur_g >= 0) atomicAdd(&sites_g[(size_t)cur_g*64 + lane], gacc);
}

// ---------- kernel 5: state update (1000 graphs, one wave each) ----------
__global__ __launch_bounds__(64) void state_kernel(
    const float* __restrict__ states2, const float* __restrict__ bonds_g, const float* __restrict__ sites_g,
    const int* __restrict__ g2b, const int* __restrict__ g2s,
    const float* __restrict__ w_stu1, const float* __restrict__ w_stu2, const float* __restrict__ b_stu2,
    const float* __restrict__ w_stu3, const float* __restrict__ b_stu3,
    const float* __restrict__ statec_stu, float* __restrict__ out_states)
{
  __shared__ float W1a[4096], W1b[4096], W2[2048], W3[2048];
  __shared__ float B2s[32], B3s[64];
  __shared__ alignas(16) float xb[64], xsit[64], hsx[64], h2x[32];
  __shared__ int cnts[2];
  int lane = threadIdx.x; int g = blockIdx.x;
  stage_w<4096>(W1a, w_stu1,         lane, 64);
  stage_w<4096>(W1b, w_stu1 + 64*64, lane, 64);
  stage_w<2048>(W2,  w_stu2,         lane, 64);
  stage_w<2048>(W3,  w_stu3,         lane, 64);
  stage_b(B2s, b_stu2, 32, lane); stage_b(B3s, b_stu3, 64, lane);
  if (lane == 0){
    cnts[0] = lbound(g2b, N_BONDS, g+1) - lbound(g2b, N_BONDS, g);
    cnts[1] = lbound(g2s, N_SITES, g+1) - lbound(g2s, N_SITES, g);
  }
  __syncthreads();
  float invb = 1.f / fmaxf((float)cnts[0], 1.f);
  float invs = 1.f / fmaxf((float)cnts[1], 1.f);
  xb[lane]   = bonds_g[(size_t)g*64 + lane] * invb;
  xsit[lane] = sites_g[(size_t)g*64 + lane] * invs;
  __syncthreads();
  {
    float a = statec_stu[(size_t)g*64 + lane];
    layerR<64,64,1,64>(W1a, xb,   &a, lane);
    layerR<64,64,1,64>(W1b, xsit, &a, lane);
    hsx[lane] = fmaxf(a, 0.f);
  }
  __syncthreads();
  {
    int j = lane & 31;
    float a = B2s[j];
    layerR<64,32,1,64>(W2, hsx, &a, j);
    if (lane < 32) h2x[lane] = fmaxf(a, 0.f);
  }
  __syncthreads();
  {
    float a = B3s[lane];
    layerR<32,64,1,32>(W3, h2x, &a, lane);
    out_states[(size_t)g*64 + lane] = fmaxf(a, 0.f) + states2[(size_t)g*64 + lane];
  }
}

// ---------- launch ----------
extern "C" void kernel_launch(void* const* d_in, const int* in_sizes, int n_in,
                              void* d_out, int out_size, void* d_ws, size_t ws_size,
                              hipStream_t stream)
{
  const float* sites   = (const float*)d_in[0];
  const float* bonds   = (const float*)d_in[1];
  const float* states  = (const float*)d_in[2];
  const float* w_sites1 = (const float*)d_in[3];  const float* b_sites1 = (const float*)d_in[4];
  const float* w_sites2 = (const float*)d_in[5];  const float* b_sites2 = (const float*)d_in[6];
  const float* w_bonds1 = (const float*)d_in[7];  const float* b_bonds1 = (const float*)d_in[8];
  const float* w_bonds2 = (const float*)d_in[9];  const float* b_bonds2 = (const float*)d_in[10];
  const float* w_states1= (const float*)d_in[11]; const float* b_states1= (const float*)d_in[12];
  const float* w_states2= (const float*)d_in[13]; const float* b_states2= (const float*)d_in[14];
  const float* w_bu1 = (const float*)d_in[15]; const float* b_bu1 = (const float*)d_in[16];
  const float* w_bu2 = (const float*)d_in[17]; const float* b_bu2 = (const float*)d_in[18];
  const float* w_bu3 = (const float*)d_in[19]; const float* b_bu3 = (const float*)d_in[20];
  const float* w_su1 = (const float*)d_in[21]; const float* b_su1 = (const float*)d_in[22];
  const float* w_su2 = (const float*)d_in[23]; const float* b_su2 = (const float*)d_in[24];
  const float* w_su3 = (const float*)d_in[25]; const float* b_su3 = (const float*)d_in[26];
  const float* w_stu1= (const float*)d_in[27]; const float* b_stu1= (const float*)d_in[28];
  const float* w_stu2= (const float*)d_in[29]; const float* b_stu2= (const float*)d_in[30];
  const float* w_stu3= (const float*)d_in[31]; const float* b_stu3= (const float*)d_in[32];
  const int* idx1 = (const int*)d_in[33];
  const int* idx2 = (const int*)d_in[34];
  const int* g2s  = (const int*)d_in[35];
  const int* g2b  = (const int*)d_in[36];

  // d_ws usage: ~27.6 MB
  float* p = (float*)d_ws;
  float* bonds_pool = p;        p += (size_t)N_SITES*64;     // zeroed
  float* bonds_g    = p;        p += (size_t)N_GRAPHS*64;    // zeroed
  float* sites_g    = p;        p += (size_t)N_GRAPHS*64;    // zeroed
  int*   cnt_pool   = (int*)p;  p += N_SITES;                // zeroed
  float* states2    = p;        p += (size_t)N_GRAPHS*64;
  float* statec_bu  = p;        p += (size_t)N_GRAPHS*64;
  float* statec_su  = p;        p += (size_t)N_GRAPHS*64;
  float* statec_stu = p;        p += (size_t)N_GRAPHS*64;

  size_t zero_bytes = ((size_t)N_SITES*64 + 2*(size_t)N_GRAPHS*64 + (size_t)N_SITES) * 4;
  hipMemsetAsync(d_ws, 0, zero_bytes, stream);

  float* out_sites  = (float*)d_out;
  float* out_bonds  = out_sites + (size_t)N_SITES*64;
  float* out_states = out_bonds + (size_t)N_BONDS*64;
  float* sites2     = out_sites;   // fp32 sites2 staged in the sites output region

  hipLaunchKernelGGL(prep_small_kernel, dim3(250), dim3(256), 0, stream,
      states, w_states1, b_states1, w_states2, b_states2,
      w_bu1, b_bu1, w_su1, b_su1, w_stu1, b_stu1,
      states2, statec_bu, statec_su, statec_stu);

  hipLaunchKernelGGL(sites_pre_kernel, dim3(1024), dim3(256), 0, stream,
      sites, w_sites1, b_sites1, w_sites2, b_sites2, sites2);

  // 12500 wave-blocks of 64 bonds, 4 waves/block -> 3125 blocks (no tail)
  hipLaunchKernelGGL(bond_kernel, dim3(3125), dim3(256), 0, stream,
      bonds, w_bonds1, b_bonds1, w_bonds2, b_bonds2,
      w_bu1, w_bu2, b_bu2, w_bu3, b_bu3,
      idx1, idx2, g2b, sites2, statec_bu,
      bonds_pool, cnt_pool, bonds_g, out_bonds);

  hipLaunchKernelGGL(site_kernel, dim3(782), dim3(512), 0, stream,
      sites2, bonds_pool, cnt_pool, g2s, statec_su,
      w_su1, w_su2, b_su2, w_su3, b_su3,
      sites_g, out_sites);

  hipLaunchKernelGGL(state_kernel, dim3(1000), dim3(64), 0, stream,
      states2, bonds_g, sites_g, g2b, g2s,
      w_stu1, w_stu2, b_stu2, w_stu3, b_stu3,
      statec_stu, out_states);
}